// Round 3
// baseline (7221.938 us; speedup 1.0000x reference)
//
#include <hip/hip_runtime.h>

#define FDIM 128
#define BN_EPS 1e-5f
#define N_FALLBACK 100000
#define E_FALLBACK 1600000

__device__ __forceinline__ float bf2f(unsigned short u) {
    union { unsigned int i; float f; } v; v.i = ((unsigned int)u) << 16; return v.f;
}
__device__ __forceinline__ unsigned short f2bf(float f) {
    union { float f2; unsigned int i; } v; v.f2 = f;
    unsigned int r = v.i + 0x7FFFu + ((v.i >> 16) & 1u);  // round-to-nearest-even
    return (unsigned short)(r >> 16);
}

// ---------------------------------------------------------------------------
// Kernel 1 (1 block): detect edge-index width + float dtype; convert params
// to f32 copies in workspace.  flags[0]=ei_is_int64, flags[1]=floats_are_f32.
// ---------------------------------------------------------------------------
__global__ void detect_convert_kernel(
    const unsigned int* __restrict__ xw, const int* __restrict__ ei,
    const void* __restrict__ Wl, const void* __restrict__ bl,
    const void* __restrict__ Wr, const void* __restrict__ gm,
    const void* __restrict__ bt,
    float* __restrict__ Wl32, float* __restrict__ Wr32,
    float* __restrict__ bl32, float* __restrict__ gm32, float* __restrict__ bt32,
    int* __restrict__ flags)
{
    __shared__ int s_f32;
    if (threadIdx.x == 0) {
        int any = 0;
        for (int k = 0; k < 128; ++k) any |= ei[2 * k + 1];
        flags[0] = (any == 0) ? 1 : 0;
        // bf16 vs f32: for f32 data the low 16 bits are random mantissa bits,
        // which are implausible bf16 values; for bf16 data they are N(0,1).
        int cnt = 0;
        for (int k = 0; k < 128; ++k) {
            unsigned short h = (unsigned short)(xw[k] & 0xFFFFu);
            int e = (h >> 7) & 0xFF;
            cnt += (h == 0 || (e >= 116 && e <= 133)) ? 1 : 0;
        }
        int f32 = (cnt < 64) ? 1 : 0;
        flags[1] = f32;
        s_f32 = f32;
    }
    __syncthreads();
    int f32 = s_f32;
    for (int i = threadIdx.x; i < FDIM * FDIM; i += blockDim.x) {
        Wl32[i] = f32 ? ((const float*)Wl)[i] : bf2f(((const unsigned short*)Wl)[i]);
        Wr32[i] = f32 ? ((const float*)Wr)[i] : bf2f(((const unsigned short*)Wr)[i]);
    }
    for (int i = threadIdx.x; i < FDIM; i += blockDim.x) {
        bl32[i] = f32 ? ((const float*)bl)[i] : bf2f(((const unsigned short*)bl)[i]);
        gm32[i] = f32 ? ((const float*)gm)[i] : bf2f(((const unsigned short*)gm)[i]);
        bt32[i] = f32 ? ((const float*)bt)[i] : bf2f(((const unsigned short*)bt)[i]);
    }
}

// ---------------------------------------------------------------------------
// Kernel 2: zero the f32 accumulators (agg, deg, col_sum, col_sq).
// ---------------------------------------------------------------------------
__global__ __launch_bounds__(256) void zero_kernel(float* __restrict__ z, long long n)
{
    long long i = (long long)blockIdx.x * 256 + threadIdx.x;
    long long stride = (long long)gridDim.x * 256;
    for (; i < n; i += stride) z[i] = 0.0f;
}

// ---------------------------------------------------------------------------
// Kernel 3: scatter-add x[src] into agg[dst] + degree count.
// 16 threads/edge, 8 features each.
// ---------------------------------------------------------------------------
__global__ __launch_bounds__(256) void scatter_kernel(
    const void* __restrict__ xv, const int* __restrict__ ei,
    float* __restrict__ agg, float* __restrict__ deg,
    const int* __restrict__ flags, int E, int N)
{
    long long idx = (long long)blockIdx.x * 256 + threadIdx.x;
    if (idx >= (long long)E * 16) return;
    int e = (int)(idx >> 4);
    int g = (int)(idx & 15);
    int src, dst;
    if (flags[0]) { src = ei[2 * e]; dst = ei[2 * (E + e)]; }
    else          { src = ei[e];     dst = ei[E + e]; }
    if ((unsigned)src >= (unsigned)N || (unsigned)dst >= (unsigned)N) return;
    float v[8];
    if (flags[1]) {
        const float4* xr = (const float4*)xv;
        float4 a = xr[(long long)src * 32 + g * 2];
        float4 b = xr[(long long)src * 32 + g * 2 + 1];
        v[0] = a.x; v[1] = a.y; v[2] = a.z; v[3] = a.w;
        v[4] = b.x; v[5] = b.y; v[6] = b.z; v[7] = b.w;
    } else {
        const uint4* xr = (const uint4*)xv;
        uint4 p = xr[(long long)src * 16 + g];
        v[0] = bf2f((unsigned short)(p.x & 0xFFFF)); v[1] = bf2f((unsigned short)(p.x >> 16));
        v[2] = bf2f((unsigned short)(p.y & 0xFFFF)); v[3] = bf2f((unsigned short)(p.y >> 16));
        v[4] = bf2f((unsigned short)(p.z & 0xFFFF)); v[5] = bf2f((unsigned short)(p.z >> 16));
        v[6] = bf2f((unsigned short)(p.w & 0xFFFF)); v[7] = bf2f((unsigned short)(p.w >> 16));
    }
    float* a = agg + (long long)dst * FDIM + g * 8;
    #pragma unroll
    for (int j = 0; j < 8; ++j) atomicAdd(a + j, v[j]);
    if (g == 0) atomicAdd(deg + dst, 1.0f);
}

// ---------------------------------------------------------------------------
// Kernel 4: h = relu(mean @ Wl^T + bl + x @ Wr^T) -> out (dtype per flag),
// plus per-feature sum / sum-of-squares for BatchNorm.
// Block = 512 threads = 4 node-slots x 128 feature-threads.
// ---------------------------------------------------------------------------
__global__ __launch_bounds__(512) void gemm_kernel(
    const float* __restrict__ agg, const float* __restrict__ deg,
    const void* __restrict__ xv,
    const float* __restrict__ Wl32, const float* __restrict__ bl32,
    const float* __restrict__ Wr32,
    void* __restrict__ out,
    float* __restrict__ col_sum, float* __restrict__ col_sq,
    const int* __restrict__ flags, int nodes)
{
    __shared__ float mrow[4][FDIM];
    __shared__ float xrow[4][FDIM];
    int tid  = threadIdx.x;
    int slot = tid >> 7;
    int d    = tid & 127;
    int f32  = flags[1];
    float lsum = 0.0f, lsq = 0.0f;
    int ngroups = (nodes + 3) >> 2;
    for (int g = blockIdx.x; g < ngroups; g += gridDim.x) {
        int n = g * 4 + slot;
        __syncthreads();
        if (n < nodes) {
            float inv = 1.0f / fmaxf(deg[n], 1.0f);
            mrow[slot][d] = agg[(long long)n * FDIM + d] * inv;
            xrow[slot][d] = f32 ? ((const float*)xv)[(long long)n * FDIM + d]
                                : bf2f(((const unsigned short*)xv)[(long long)n * FDIM + d]);
        }
        __syncthreads();
        if (n < nodes) {
            float acc = bl32[d];
            const float4* wl4 = (const float4*)(Wl32 + d * FDIM);
            const float4* wr4 = (const float4*)(Wr32 + d * FDIM);
            const float* mr = mrow[slot];
            const float* xr = xrow[slot];
            #pragma unroll
            for (int c = 0; c < 32; ++c) {
                float4 wa = wl4[c];
                float4 wb = wr4[c];
                int k = c * 4;
                acc += wa.x * mr[k] + wa.y * mr[k + 1] + wa.z * mr[k + 2] + wa.w * mr[k + 3];
                acc += wb.x * xr[k] + wb.y * xr[k + 1] + wb.z * xr[k + 2] + wb.w * xr[k + 3];
            }
            acc = fmaxf(acc, 0.0f);
            if (f32) ((float*)out)[(long long)n * FDIM + d] = acc;
            else     ((unsigned short*)out)[(long long)n * FDIM + d] = f2bf(acc);
            lsum += acc;
            lsq  += acc * acc;
        }
    }
    // block-level reduction over the 4 slots, then one atomic per feature
    __syncthreads();
    mrow[slot][d] = lsum;
    xrow[slot][d] = lsq;
    __syncthreads();
    if (slot == 0) {
        atomicAdd(&col_sum[d], mrow[0][d] + mrow[1][d] + mrow[2][d] + mrow[3][d]);
        atomicAdd(&col_sq[d],  xrow[0][d] + xrow[1][d] + xrow[2][d] + xrow[3][d]);
    }
}

// ---------------------------------------------------------------------------
// Kernel 5: per-feature BN scale/shift.
// ---------------------------------------------------------------------------
__global__ void bn_prep(const float* __restrict__ col_sum, const float* __restrict__ col_sq,
                        const float* __restrict__ gm32, const float* __restrict__ bt32,
                        float* __restrict__ scale, float* __restrict__ shift, int nodes)
{
    int d = threadIdx.x;
    float invN = 1.0f / (float)nodes;
    float mu  = col_sum[d] * invN;
    float var = col_sq[d] * invN - mu * mu;
    float sc  = gm32[d] * rsqrtf(var + BN_EPS);
    scale[d] = sc;
    shift[d] = bt32[d] - mu * sc;
}

// ---------------------------------------------------------------------------
// Kernel 6: in-place BN affine on out (dtype per flag).
// ---------------------------------------------------------------------------
__global__ __launch_bounds__(256) void ChemSageBlock_89206470738295_kernel(
    void* __restrict__ hv,
    const float* __restrict__ scale, const float* __restrict__ shift,
    const int* __restrict__ flags, long long nd)
{
    long long idx = (long long)blockIdx.x * 256 + threadIdx.x;
    if (flags[1]) {
        long long tot = nd >> 2;                 // float4 per thread
        if (idx >= tot) return;
        int d0 = (int)(idx & 31) * 4;
        float4 p = ((float4*)hv)[idx];
        p.x = p.x * scale[d0 + 0] + shift[d0 + 0];
        p.y = p.y * scale[d0 + 1] + shift[d0 + 1];
        p.z = p.z * scale[d0 + 2] + shift[d0 + 2];
        p.w = p.w * scale[d0 + 3] + shift[d0 + 3];
        ((float4*)hv)[idx] = p;
    } else {
        long long tot = nd >> 3;                 // 8 bf16 per thread
        if (idx >= tot) return;
        int d0 = (int)(idx & 15) * 8;
        uint4 p = ((uint4*)hv)[idx];
        unsigned int q[4] = {p.x, p.y, p.z, p.w};
        #pragma unroll
        for (int j = 0; j < 4; ++j) {
            int dd = d0 + j * 2;
            float lo = bf2f((unsigned short)(q[j] & 0xFFFF));
            float hi = bf2f((unsigned short)(q[j] >> 16));
            lo = lo * scale[dd]     + shift[dd];
            hi = hi * scale[dd + 1] + shift[dd + 1];
            q[j] = (unsigned int)f2bf(lo) | ((unsigned int)f2bf(hi) << 16);
        }
        uint4 r; r.x = q[0]; r.y = q[1]; r.z = q[2]; r.w = q[3];
        ((uint4*)hv)[idx] = r;
    }
}

// ---------------------------------------------------------------------------
extern "C" __attribute__((visibility("default")))
void kernel_launch(void* const* d_in, const int* in_sizes, int n_in,
                   void* d_out, int out_size, void* d_ws, size_t ws_size,
                   hipStream_t stream)
{
    int N = N_FALLBACK, E = E_FALLBACK;
    if (in_sizes) {
        if (in_sizes[0] > 0 && (in_sizes[0] % FDIM) == 0) N = in_sizes[0] / FDIM;
        if (in_sizes[1] > 0 && (in_sizes[1] % 2) == 0)    E = in_sizes[1] / 2;
    }
    const void* x  = d_in[0];
    const int*  ei = (const int*)d_in[1];
    const void* Wl = d_in[2];
    const void* bl = d_in[3];
    const void* Wr = d_in[4];
    const void* gm = d_in[5];
    const void* bt = d_in[6];

    // ws layout (f32): agg[N*128] | deg[N] | col_sum[128] | col_sq[128] |
    //                  scale[128] | shift[128] | Wl32[16384] | Wr32[16384] |
    //                  bl32[128] | gm32[128] | bt32[128] | flags[2]
    float* agg     = (float*)d_ws;
    float* deg     = agg + (size_t)N * FDIM;
    float* col_sum = deg + N;
    float* col_sq  = col_sum + FDIM;
    float* scale   = col_sq + FDIM;
    float* shift   = scale + FDIM;
    float* Wl32    = shift + FDIM;
    float* Wr32    = Wl32 + FDIM * FDIM;
    float* bl32    = Wr32 + FDIM * FDIM;
    float* gm32    = bl32 + FDIM;
    float* bt32    = gm32 + FDIM;
    int*   flags   = (int*)(bt32 + FDIM);

    detect_convert_kernel<<<1, 256, 0, stream>>>(
        (const unsigned int*)x, ei, Wl, bl, Wr, gm, bt,
        Wl32, Wr32, bl32, gm32, bt32, flags);

    long long zcount = (long long)N * FDIM + N + 2 * FDIM;
    zero_kernel<<<2048, 256, 0, stream>>>(agg, zcount);

    long long sc_threads = (long long)E * 16;
    scatter_kernel<<<(int)((sc_threads + 255) / 256), 256, 0, stream>>>(
        x, ei, agg, deg, flags, E, N);

    gemm_kernel<<<2048, 512, 0, stream>>>(agg, deg, x, Wl32, bl32, Wr32,
                                          d_out, col_sum, col_sq, flags, N);

    bn_prep<<<1, 128, 0, stream>>>(col_sum, col_sq, gm32, bt32, scale, shift, N);

    long long nd = (long long)N * FDIM;
    ChemSageBlock_89206470738295_kernel<<<(int)((nd / 4 + 255) / 256), 256, 0, stream>>>(
        d_out, scale, shift, flags, nd);
}

// Round 4
// 1981.819 us; speedup vs baseline: 3.6441x; 3.6441x over previous
//
#include <hip/hip_runtime.h>

#define FDIM 128
#define BN_EPS 1e-5f

__device__ __forceinline__ float bf2f(unsigned short u) {
    union { unsigned int i; float f; } v; v.i = ((unsigned int)u) << 16; return v.f;
}
__device__ __forceinline__ unsigned short f2bf(float f) {
    union { float f2; unsigned int i; } v; v.f2 = f;
    unsigned int r = v.i + 0x7FFFu + ((v.i >> 16) & 1u);  // round-to-nearest-even
    return (unsigned short)(r >> 16);
}

// ---------------------------------------------------------------------------
// Kernel 1 (1 block): detect edge-index width + float dtype; convert params
// to f32 copies in workspace.  flags[0]=ei_is_int64, flags[1]=floats_are_f32.
// ---------------------------------------------------------------------------
__global__ void detect_convert_kernel(
    const unsigned int* __restrict__ xw, const int* __restrict__ ei,
    const void* __restrict__ Wl, const void* __restrict__ bl,
    const void* __restrict__ Wr, const void* __restrict__ gm,
    const void* __restrict__ bt,
    float* __restrict__ Wl32, float* __restrict__ Wr32,
    float* __restrict__ bl32, float* __restrict__ gm32, float* __restrict__ bt32,
    int* __restrict__ flags)
{
    __shared__ int s_f32;
    if (threadIdx.x == 0) {
        int any = 0;
        for (int k = 0; k < 128; ++k) any |= ei[2 * k + 1];
        flags[0] = (any == 0) ? 1 : 0;
        int cnt = 0;
        for (int k = 0; k < 128; ++k) {
            unsigned short h = (unsigned short)(xw[k] & 0xFFFFu);
            int e = (h >> 7) & 0xFF;
            cnt += (h == 0 || (e >= 116 && e <= 133)) ? 1 : 0;
        }
        int f32 = (cnt < 64) ? 1 : 0;
        flags[1] = f32;
        s_f32 = f32;
    }
    __syncthreads();
    int f32 = s_f32;
    for (int i = threadIdx.x; i < FDIM * FDIM; i += blockDim.x) {
        Wl32[i] = f32 ? ((const float*)Wl)[i] : bf2f(((const unsigned short*)Wl)[i]);
        Wr32[i] = f32 ? ((const float*)Wr)[i] : bf2f(((const unsigned short*)Wr)[i]);
    }
    for (int i = threadIdx.x; i < FDIM; i += blockDim.x) {
        bl32[i] = f32 ? ((const float*)bl)[i] : bf2f(((const unsigned short*)bl)[i]);
        gm32[i] = f32 ? ((const float*)gm)[i] : bf2f(((const unsigned short*)gm)[i]);
        bt32[i] = f32 ? ((const float*)bt)[i] : bf2f(((const unsigned short*)bt)[i]);
    }
}

// ---------------------------------------------------------------------------
__global__ __launch_bounds__(256) void zero_kernel(float* __restrict__ z, long long n)
{
    long long i = (long long)blockIdx.x * 256 + threadIdx.x;
    long long stride = (long long)gridDim.x * 256;
    for (; i < n; i += stride) z[i] = 0.0f;
}

__device__ __forceinline__ int edge_at(const int* ei, long long pos, int is64) {
    return is64 ? ei[2 * pos] : ei[pos];
}

// ---------------------------------------------------------------------------
// CSR phase 1: in-degree counts (int atomics on 0.4 MB — L2-friendly).
// ---------------------------------------------------------------------------
__global__ __launch_bounds__(256) void count_kernel(
    const int* __restrict__ ei, int* __restrict__ cnt,
    const int* __restrict__ flags, int E, int N)
{
    int e = blockIdx.x * 256 + threadIdx.x;
    if (e >= E) return;
    int dst = edge_at(ei, (long long)E + e, flags[0]);
    if ((unsigned)dst < (unsigned)N) atomicAdd(&cnt[dst], 1);
}

// ---------------------------------------------------------------------------
// CSR phase 2: exclusive scan of cnt[0..N) -> row_start[0..N], single block.
// Each of 1024 threads serially sums a chunk, Hillis-Steele across partials,
// then serially writes back running offsets.
// ---------------------------------------------------------------------------
__global__ __launch_bounds__(1024) void scan_kernel(
    const int* __restrict__ cnt, int* __restrict__ row_start, int N)
{
    __shared__ int part[1024];
    int t = threadIdx.x;
    int chunk = (N + 1023) / 1024;
    int lo = t * chunk; if (lo > N) lo = N;
    int hi = lo + chunk; if (hi > N) hi = N;
    int s = 0;
    for (int i = lo; i < hi; ++i) s += cnt[i];
    part[t] = s;
    __syncthreads();
    for (int off = 1; off < 1024; off <<= 1) {
        int v = (t >= off) ? part[t - off] : 0;
        __syncthreads();
        part[t] += v;
        __syncthreads();
    }
    int run = (t == 0) ? 0 : part[t - 1];   // exclusive prefix of this chunk
    for (int i = lo; i < hi; ++i) { row_start[i] = run; run += cnt[i]; }
    if (hi == N) row_start[N] = run;        // trailing threads write total too
}

// ---------------------------------------------------------------------------
// CSR phase 3: bucket-fill edge sources per destination.
// ---------------------------------------------------------------------------
__global__ __launch_bounds__(256) void fill_kernel(
    const int* __restrict__ ei, const int* __restrict__ row_start,
    int* __restrict__ cursor, int* __restrict__ csr_src,
    const int* __restrict__ flags, int E, int N)
{
    int e = blockIdx.x * 256 + threadIdx.x;
    if (e >= E) return;
    int is64 = flags[0];
    int src = edge_at(ei, e, is64);
    int dst = edge_at(ei, (long long)E + e, is64);
    if ((unsigned)src >= (unsigned)N || (unsigned)dst >= (unsigned)N) return;
    int pos = atomicAdd(&cursor[dst], 1);
    csr_src[row_start[dst] + pos] = src;
}

// ---------------------------------------------------------------------------
// CSR phase 4: per-node gather + mean. One wave per node:
// lanes = 4 edge-slots x 16 feature-groups (8 features each).
// ---------------------------------------------------------------------------
__global__ __launch_bounds__(256) void aggregate_kernel(
    const void* __restrict__ xv, const int* __restrict__ csr_src,
    const int* __restrict__ row_start, float* __restrict__ agg,
    const int* __restrict__ flags, int N)
{
    int wave = threadIdx.x >> 6;
    int lane = threadIdx.x & 63;
    int n = blockIdx.x * 4 + wave;
    if (n >= N) return;
    int g = lane & 15, slot = lane >> 4;
    int start = row_start[n], end = row_start[n + 1];
    int f32 = flags[1];
    float acc[8] = {0, 0, 0, 0, 0, 0, 0, 0};
    for (int i = start + slot; i < end; i += 4) {
        int src = csr_src[i];
        if (f32) {
            const float4* xr = (const float4*)xv;
            float4 a = xr[(long long)src * 32 + g * 2];
            float4 b = xr[(long long)src * 32 + g * 2 + 1];
            acc[0] += a.x; acc[1] += a.y; acc[2] += a.z; acc[3] += a.w;
            acc[4] += b.x; acc[5] += b.y; acc[6] += b.z; acc[7] += b.w;
        } else {
            uint4 p = ((const uint4*)xv)[(long long)src * 16 + g];
            acc[0] += bf2f((unsigned short)(p.x & 0xFFFF));
            acc[1] += bf2f((unsigned short)(p.x >> 16));
            acc[2] += bf2f((unsigned short)(p.y & 0xFFFF));
            acc[3] += bf2f((unsigned short)(p.y >> 16));
            acc[4] += bf2f((unsigned short)(p.z & 0xFFFF));
            acc[5] += bf2f((unsigned short)(p.z >> 16));
            acc[6] += bf2f((unsigned short)(p.w & 0xFFFF));
            acc[7] += bf2f((unsigned short)(p.w >> 16));
        }
    }
    #pragma unroll
    for (int j = 0; j < 8; ++j) {
        acc[j] += __shfl_xor(acc[j], 16, 64);
        acc[j] += __shfl_xor(acc[j], 32, 64);
    }
    if (slot == 0) {
        float inv = 1.0f / fmaxf((float)(end - start), 1.0f);
        float4 a, b;
        a.x = acc[0] * inv; a.y = acc[1] * inv; a.z = acc[2] * inv; a.w = acc[3] * inv;
        b.x = acc[4] * inv; b.y = acc[5] * inv; b.z = acc[6] * inv; b.w = acc[7] * inv;
        float4* ag = (float4*)(agg + (long long)n * FDIM + g * 8);
        ag[0] = a; ag[1] = b;
    }
}

// ---------------------------------------------------------------------------
// Fallback scatter (atomic path) — used only if ws_size is too small for CSR.
// ---------------------------------------------------------------------------
__global__ __launch_bounds__(256) void scatter_kernel(
    const void* __restrict__ xv, const int* __restrict__ ei,
    float* __restrict__ agg, float* __restrict__ deg,
    const int* __restrict__ flags, int E, int N)
{
    long long idx = (long long)blockIdx.x * 256 + threadIdx.x;
    if (idx >= (long long)E * 16) return;
    int e = (int)(idx >> 4);
    int g = (int)(idx & 15);
    int is64 = flags[0];
    int src = edge_at(ei, e, is64);
    int dst = edge_at(ei, (long long)E + e, is64);
    if ((unsigned)src >= (unsigned)N || (unsigned)dst >= (unsigned)N) return;
    float v[8];
    if (flags[1]) {
        const float4* xr = (const float4*)xv;
        float4 a = xr[(long long)src * 32 + g * 2];
        float4 b = xr[(long long)src * 32 + g * 2 + 1];
        v[0] = a.x; v[1] = a.y; v[2] = a.z; v[3] = a.w;
        v[4] = b.x; v[5] = b.y; v[6] = b.z; v[7] = b.w;
    } else {
        uint4 p = ((const uint4*)xv)[(long long)src * 16 + g];
        v[0] = bf2f((unsigned short)(p.x & 0xFFFF)); v[1] = bf2f((unsigned short)(p.x >> 16));
        v[2] = bf2f((unsigned short)(p.y & 0xFFFF)); v[3] = bf2f((unsigned short)(p.y >> 16));
        v[4] = bf2f((unsigned short)(p.z & 0xFFFF)); v[5] = bf2f((unsigned short)(p.z >> 16));
        v[6] = bf2f((unsigned short)(p.w & 0xFFFF)); v[7] = bf2f((unsigned short)(p.w >> 16));
    }
    float* a = agg + (long long)dst * FDIM + g * 8;
    #pragma unroll
    for (int j = 0; j < 8; ++j) atomicAdd(a + j, v[j]);
    if (g == 0) atomicAdd(deg + dst, 1.0f);
}

// ---------------------------------------------------------------------------
// GEMM: h = relu(mean @ Wl^T + bl + x @ Wr^T) -> out, plus BN stats.
// Block = 512 threads = 4 node-slots x 128 feature-threads.
// mean_ready=1: agg already holds the mean; else divide by deg.
// ---------------------------------------------------------------------------
__global__ __launch_bounds__(512) void gemm_kernel(
    const float* __restrict__ agg, const float* __restrict__ deg,
    const void* __restrict__ xv,
    const float* __restrict__ Wl32, const float* __restrict__ bl32,
    const float* __restrict__ Wr32,
    void* __restrict__ out,
    float* __restrict__ col_sum, float* __restrict__ col_sq,
    const int* __restrict__ flags, int nodes, int mean_ready)
{
    __shared__ float mrow[4][FDIM];
    __shared__ float xrow[4][FDIM];
    int tid  = threadIdx.x;
    int slot = tid >> 7;
    int d    = tid & 127;
    int f32  = flags[1];
    float lsum = 0.0f, lsq = 0.0f;
    int ngroups = (nodes + 3) >> 2;
    for (int g = blockIdx.x; g < ngroups; g += gridDim.x) {
        int n = g * 4 + slot;
        __syncthreads();
        if (n < nodes) {
            float inv = mean_ready ? 1.0f : 1.0f / fmaxf(deg[n], 1.0f);
            mrow[slot][d] = agg[(long long)n * FDIM + d] * inv;
            xrow[slot][d] = f32 ? ((const float*)xv)[(long long)n * FDIM + d]
                                : bf2f(((const unsigned short*)xv)[(long long)n * FDIM + d]);
        }
        __syncthreads();
        if (n < nodes) {
            float acc = bl32[d];
            const float4* wl4 = (const float4*)(Wl32 + d * FDIM);
            const float4* wr4 = (const float4*)(Wr32 + d * FDIM);
            const float* mr = mrow[slot];
            const float* xr = xrow[slot];
            #pragma unroll
            for (int c = 0; c < 32; ++c) {
                float4 wa = wl4[c];
                float4 wb = wr4[c];
                int k = c * 4;
                acc += wa.x * mr[k] + wa.y * mr[k + 1] + wa.z * mr[k + 2] + wa.w * mr[k + 3];
                acc += wb.x * xr[k] + wb.y * xr[k + 1] + wb.z * xr[k + 2] + wb.w * xr[k + 3];
            }
            acc = fmaxf(acc, 0.0f);
            if (f32) ((float*)out)[(long long)n * FDIM + d] = acc;
            else     ((unsigned short*)out)[(long long)n * FDIM + d] = f2bf(acc);
            lsum += acc;
            lsq  += acc * acc;
        }
    }
    __syncthreads();
    mrow[slot][d] = lsum;
    xrow[slot][d] = lsq;
    __syncthreads();
    if (slot == 0) {
        atomicAdd(&col_sum[d], mrow[0][d] + mrow[1][d] + mrow[2][d] + mrow[3][d]);
        atomicAdd(&col_sq[d],  xrow[0][d] + xrow[1][d] + xrow[2][d] + xrow[3][d]);
    }
}

// ---------------------------------------------------------------------------
__global__ void bn_prep(const float* __restrict__ col_sum, const float* __restrict__ col_sq,
                        const float* __restrict__ gm32, const float* __restrict__ bt32,
                        float* __restrict__ scale, float* __restrict__ shift, int nodes)
{
    int d = threadIdx.x;
    float invN = 1.0f / (float)nodes;
    float mu  = col_sum[d] * invN;
    float var = col_sq[d] * invN - mu * mu;
    float sc  = gm32[d] * rsqrtf(var + BN_EPS);
    scale[d] = sc;
    shift[d] = bt32[d] - mu * sc;
}

// ---------------------------------------------------------------------------
__global__ __launch_bounds__(256) void ChemSageBlock_89206470738295_kernel(
    void* __restrict__ hv,
    const float* __restrict__ scale, const float* __restrict__ shift,
    const int* __restrict__ flags, long long nd)
{
    long long idx = (long long)blockIdx.x * 256 + threadIdx.x;
    if (flags[1]) {
        long long tot = nd >> 2;
        if (idx >= tot) return;
        int d0 = (int)(idx & 31) * 4;
        float4 p = ((float4*)hv)[idx];
        p.x = p.x * scale[d0 + 0] + shift[d0 + 0];
        p.y = p.y * scale[d0 + 1] + shift[d0 + 1];
        p.z = p.z * scale[d0 + 2] + shift[d0 + 2];
        p.w = p.w * scale[d0 + 3] + shift[d0 + 3];
        ((float4*)hv)[idx] = p;
    } else {
        long long tot = nd >> 3;
        if (idx >= tot) return;
        int d0 = (int)(idx & 15) * 8;
        uint4 p = ((uint4*)hv)[idx];
        unsigned int q[4] = {p.x, p.y, p.z, p.w};
        #pragma unroll
        for (int j = 0; j < 4; ++j) {
            int dd = d0 + j * 2;
            float lo = bf2f((unsigned short)(q[j] & 0xFFFF));
            float hi = bf2f((unsigned short)(q[j] >> 16));
            lo = lo * scale[dd]     + shift[dd];
            hi = hi * scale[dd + 1] + shift[dd + 1];
            q[j] = (unsigned int)f2bf(lo) | ((unsigned int)f2bf(hi) << 16);
        }
        uint4 r; r.x = q[0]; r.y = q[1]; r.z = q[2]; r.w = q[3];
        ((uint4*)hv)[idx] = r;
    }
}

// ---------------------------------------------------------------------------
extern "C" __attribute__((visibility("default")))
void kernel_launch(void* const* d_in, const int* in_sizes, int n_in,
                   void* d_out, int out_size, void* d_ws, size_t ws_size,
                   hipStream_t stream)
{
    int N = 100000, E = 1600000;
    if (in_sizes) {
        if (in_sizes[0] > 0 && (in_sizes[0] % FDIM) == 0) N = in_sizes[0] / FDIM;
        if (in_sizes[1] > 0 && (in_sizes[1] % 2) == 0)    E = in_sizes[1] / 2;
    }
    const void* x  = d_in[0];
    const int*  ei = (const int*)d_in[1];
    const void* Wl = d_in[2];
    const void* bl = d_in[3];
    const void* Wr = d_in[4];
    const void* gm = d_in[5];
    const void* bt = d_in[6];

    // ws layout (4-byte words), 16B-aligned sections:
    // agg[N*128] | Wl32[16384] | Wr32[16384] | bl32,gm32,bt32[128 ea] |
    // scale,shift[128 ea] | col_sum,col_sq[128 ea] | cnt[N] | cursor[N] |
    // row_start[N+64] | csr_src[E] | flags[16]
    float* agg     = (float*)d_ws;
    float* Wl32    = agg + (size_t)N * FDIM;
    float* Wr32    = Wl32 + FDIM * FDIM;
    float* bl32    = Wr32 + FDIM * FDIM;
    float* gm32    = bl32 + FDIM;
    float* bt32    = gm32 + FDIM;
    float* scale   = bt32 + FDIM;
    float* shift   = scale + FDIM;
    float* col_sum = shift + FDIM;
    float* col_sq  = col_sum + FDIM;
    int*   cnt     = (int*)(col_sq + FDIM);
    int*   cursor  = cnt + N;
    int*   row_st  = cursor + N;
    int*   csr_src = row_st + N + 64;
    int*   flags   = csr_src + E;
    size_t ws_need = (size_t)(flags + 16 - (int*)d_ws) * 4;

    detect_convert_kernel<<<1, 256, 0, stream>>>(
        (const unsigned int*)x, ei, Wl, bl, Wr, gm, bt,
        Wl32, Wr32, bl32, gm32, bt32, flags);

    int eblocks = (E + 255) / 256;
    if (ws_size >= ws_need) {
        // --- CSR path: no float atomics ---
        // zero: col_sum, col_sq, cnt, cursor (contiguous from col_sum)
        long long zcount = 2 * FDIM + 2 * (long long)N;
        zero_kernel<<<512, 256, 0, stream>>>(col_sum, zcount);
        count_kernel<<<eblocks, 256, 0, stream>>>(ei, cnt, flags, E, N);
        scan_kernel<<<1, 1024, 0, stream>>>(cnt, row_st, N);
        fill_kernel<<<eblocks, 256, 0, stream>>>(ei, row_st, cursor, csr_src, flags, E, N);
        aggregate_kernel<<<(N + 3) / 4, 256, 0, stream>>>(x, csr_src, row_st, agg, flags, N);
        gemm_kernel<<<2048, 512, 0, stream>>>(agg, nullptr, x, Wl32, bl32, Wr32,
                                              d_out, col_sum, col_sq, flags, N, 1);
    } else {
        // --- fallback: atomic scatter (proven correct in round 3) ---
        long long zcount = (long long)N * FDIM;      // agg
        zero_kernel<<<2048, 256, 0, stream>>>(agg, zcount);
        zero_kernel<<<512, 256, 0, stream>>>(col_sum, 2 * FDIM + (long long)N); // stats + deg(cnt)
        long long sc_threads = (long long)E * 16;
        scatter_kernel<<<(int)((sc_threads + 255) / 256), 256, 0, stream>>>(
            x, ei, agg, (float*)cnt, flags, E, N);
        gemm_kernel<<<2048, 512, 0, stream>>>(agg, (const float*)cnt, x, Wl32, bl32, Wr32,
                                              d_out, col_sum, col_sq, flags, N, 0);
    }

    bn_prep<<<1, 128, 0, stream>>>(col_sum, col_sq, gm32, bt32, scale, shift, N);

    long long nd = (long long)N * FDIM;
    ChemSageBlock_89206470738295_kernel<<<(int)((nd / 4 + 255) / 256), 256, 0, stream>>>(
        d_out, scale, shift, flags, nd);
}

// Round 5
// 1979.310 us; speedup vs baseline: 3.6487x; 1.0013x over previous
//
#include <hip/hip_runtime.h>

#define FDIM 128
#define BN_EPS 1e-5f
#define LDS_STRIDE 264   // 256 + 8 bf16 pad: spreads b128 reads over all 8 bank-groups

typedef short v8s __attribute__((ext_vector_type(8)));
typedef float v4f __attribute__((ext_vector_type(4)));

__device__ __forceinline__ float bf2f(unsigned short u) {
    union { unsigned int i; float f; } v; v.i = ((unsigned int)u) << 16; return v.f;
}
__device__ __forceinline__ unsigned short f2bf(float f) {
    union { float f2; unsigned int i; } v; v.f2 = f;
    unsigned int r = v.i + 0x7FFFu + ((v.i >> 16) & 1u);  // RNE
    return (unsigned short)(r >> 16);
}

// ---------------------------------------------------------------------------
// detect dtypes + convert params to f32.  flags[0]=ei_is_int64, flags[1]=f32.
// ---------------------------------------------------------------------------
__global__ void detect_convert_kernel(
    const unsigned int* __restrict__ xw, const int* __restrict__ ei,
    const void* __restrict__ Wl, const void* __restrict__ bl,
    const void* __restrict__ Wr, const void* __restrict__ gm,
    const void* __restrict__ bt,
    float* __restrict__ Wl32, float* __restrict__ Wr32,
    float* __restrict__ bl32, float* __restrict__ gm32, float* __restrict__ bt32,
    int* __restrict__ flags)
{
    __shared__ int s_f32;
    if (threadIdx.x == 0) {
        int any = 0;
        for (int k = 0; k < 128; ++k) any |= ei[2 * k + 1];
        flags[0] = (any == 0) ? 1 : 0;
        int cnt = 0;
        for (int k = 0; k < 128; ++k) {
            unsigned short h = (unsigned short)(xw[k] & 0xFFFFu);
            int e = (h >> 7) & 0xFF;
            cnt += (h == 0 || (e >= 116 && e <= 133)) ? 1 : 0;
        }
        int f32 = (cnt < 64) ? 1 : 0;
        flags[1] = f32;
        s_f32 = f32;
    }
    __syncthreads();
    int f32 = s_f32;
    for (int i = threadIdx.x; i < FDIM * FDIM; i += blockDim.x) {
        Wl32[i] = f32 ? ((const float*)Wl)[i] : bf2f(((const unsigned short*)Wl)[i]);
        Wr32[i] = f32 ? ((const float*)Wr)[i] : bf2f(((const unsigned short*)Wr)[i]);
    }
    for (int i = threadIdx.x; i < FDIM; i += blockDim.x) {
        bl32[i] = f32 ? ((const float*)bl)[i] : bf2f(((const unsigned short*)bl)[i]);
        gm32[i] = f32 ? ((const float*)gm)[i] : bf2f(((const unsigned short*)gm)[i]);
        bt32[i] = f32 ? ((const float*)bt)[i] : bf2f(((const unsigned short*)bt)[i]);
    }
}

// ---------------------------------------------------------------------------
__global__ __launch_bounds__(256) void zero_kernel(float* __restrict__ z, long long n)
{
    long long i = (long long)blockIdx.x * 256 + threadIdx.x;
    long long stride = (long long)gridDim.x * 256;
    for (; i < n; i += stride) z[i] = 0.0f;
}

__device__ __forceinline__ int edge_at(const int* ei, long long pos, int is64) {
    return is64 ? ei[2 * pos] : ei[pos];
}

// ---------------------------------------------------------------------------
// CSR phase 1: in-degree counts.
// ---------------------------------------------------------------------------
__global__ __launch_bounds__(256) void count_kernel(
    const int* __restrict__ ei, int* __restrict__ cnt,
    const int* __restrict__ flags, int E, int N)
{
    int e = blockIdx.x * 256 + threadIdx.x;
    if (e >= E) return;
    int dst = edge_at(ei, (long long)E + e, flags[0]);
    if ((unsigned)dst < (unsigned)N) atomicAdd(&cnt[dst], 1);
}

// ---------------------------------------------------------------------------
// CSR phase 2: exclusive scan (single block).
// ---------------------------------------------------------------------------
__global__ __launch_bounds__(1024) void scan_kernel(
    const int* __restrict__ cnt, int* __restrict__ row_start, int N)
{
    __shared__ int part[1024];
    int t = threadIdx.x;
    int chunk = (N + 1023) / 1024;
    int lo = t * chunk; if (lo > N) lo = N;
    int hi = lo + chunk; if (hi > N) hi = N;
    int s = 0;
    for (int i = lo; i < hi; ++i) s += cnt[i];
    part[t] = s;
    __syncthreads();
    for (int off = 1; off < 1024; off <<= 1) {
        int v = (t >= off) ? part[t - off] : 0;
        __syncthreads();
        part[t] += v;
        __syncthreads();
    }
    int run = (t == 0) ? 0 : part[t - 1];
    for (int i = lo; i < hi; ++i) { row_start[i] = run; run += cnt[i]; }
    if (hi == N) row_start[N] = run;
}

// ---------------------------------------------------------------------------
// CSR phase 3: bucket-fill sources per destination.
// ---------------------------------------------------------------------------
__global__ __launch_bounds__(256) void fill_kernel(
    const int* __restrict__ ei, const int* __restrict__ row_start,
    int* __restrict__ cursor, int* __restrict__ csr_src,
    const int* __restrict__ flags, int E, int N)
{
    int e = blockIdx.x * 256 + threadIdx.x;
    if (e >= E) return;
    int is64 = flags[0];
    int src = edge_at(ei, e, is64);
    int dst = edge_at(ei, (long long)E + e, is64);
    if ((unsigned)src >= (unsigned)N || (unsigned)dst >= (unsigned)N) return;
    int pos = atomicAdd(&cursor[dst], 1);
    csr_src[row_start[dst] + pos] = src;
}

// ---------------------------------------------------------------------------
// CSR phase 4: per-node gather + mean.
// ---------------------------------------------------------------------------
__global__ __launch_bounds__(256) void aggregate_kernel(
    const void* __restrict__ xv, const int* __restrict__ csr_src,
    const int* __restrict__ row_start, float* __restrict__ agg,
    unsigned short* __restrict__ mean_bf,
    const int* __restrict__ flags, int N)
{
    int wave = threadIdx.x >> 6;
    int lane = threadIdx.x & 63;
    int n = blockIdx.x * 4 + wave;
    if (n >= N) return;
    int g = lane & 15, slot = lane >> 4;
    int start = row_start[n], end = row_start[n + 1];
    int f32 = flags[1];
    float acc[8] = {0, 0, 0, 0, 0, 0, 0, 0};
    for (int i = start + slot; i < end; i += 4) {
        int src = csr_src[i];
        if (f32) {
            const float4* xr = (const float4*)xv;
            float4 a = xr[(long long)src * 32 + g * 2];
            float4 b = xr[(long long)src * 32 + g * 2 + 1];
            acc[0] += a.x; acc[1] += a.y; acc[2] += a.z; acc[3] += a.w;
            acc[4] += b.x; acc[5] += b.y; acc[6] += b.z; acc[7] += b.w;
        } else {
            uint4 p = ((const uint4*)xv)[(long long)src * 16 + g];
            acc[0] += bf2f((unsigned short)(p.x & 0xFFFF));
            acc[1] += bf2f((unsigned short)(p.x >> 16));
            acc[2] += bf2f((unsigned short)(p.y & 0xFFFF));
            acc[3] += bf2f((unsigned short)(p.y >> 16));
            acc[4] += bf2f((unsigned short)(p.z & 0xFFFF));
            acc[5] += bf2f((unsigned short)(p.z >> 16));
            acc[6] += bf2f((unsigned short)(p.w & 0xFFFF));
            acc[7] += bf2f((unsigned short)(p.w >> 16));
        }
    }
    #pragma unroll
    for (int j = 0; j < 8; ++j) {
        acc[j] += __shfl_xor(acc[j], 16, 64);
        acc[j] += __shfl_xor(acc[j], 32, 64);
    }
    if (slot == 0) {
        float inv = 1.0f / fmaxf((float)(end - start), 1.0f);
        if (f32) {
            float4 a, b;
            a.x = acc[0] * inv; a.y = acc[1] * inv; a.z = acc[2] * inv; a.w = acc[3] * inv;
            b.x = acc[4] * inv; b.y = acc[5] * inv; b.z = acc[6] * inv; b.w = acc[7] * inv;
            float4* ag = (float4*)(agg + (long long)n * FDIM + g * 8);
            ag[0] = a; ag[1] = b;
        } else {
            uint4 p;
            p.x = (unsigned int)f2bf(acc[0] * inv) | ((unsigned int)f2bf(acc[1] * inv) << 16);
            p.y = (unsigned int)f2bf(acc[2] * inv) | ((unsigned int)f2bf(acc[3] * inv) << 16);
            p.z = (unsigned int)f2bf(acc[4] * inv) | ((unsigned int)f2bf(acc[5] * inv) << 16);
            p.w = (unsigned int)f2bf(acc[6] * inv) | ((unsigned int)f2bf(acc[7] * inv) << 16);
            ((uint4*)(mean_bf + (long long)n * FDIM + g * 8))[0] = p;
        }
    }
}

// ---------------------------------------------------------------------------
// Fallback scatter (atomic path) — only if ws too small for CSR.
// ---------------------------------------------------------------------------
__global__ __launch_bounds__(256) void scatter_kernel(
    const void* __restrict__ xv, const int* __restrict__ ei,
    float* __restrict__ agg, float* __restrict__ deg,
    const int* __restrict__ flags, int E, int N)
{
    long long idx = (long long)blockIdx.x * 256 + threadIdx.x;
    if (idx >= (long long)E * 16) return;
    int e = (int)(idx >> 4);
    int g = (int)(idx & 15);
    int is64 = flags[0];
    int src = edge_at(ei, e, is64);
    int dst = edge_at(ei, (long long)E + e, is64);
    if ((unsigned)src >= (unsigned)N || (unsigned)dst >= (unsigned)N) return;
    float v[8];
    if (flags[1]) {
        const float4* xr = (const float4*)xv;
        float4 a = xr[(long long)src * 32 + g * 2];
        float4 b = xr[(long long)src * 32 + g * 2 + 1];
        v[0] = a.x; v[1] = a.y; v[2] = a.z; v[3] = a.w;
        v[4] = b.x; v[5] = b.y; v[6] = b.z; v[7] = b.w;
    } else {
        uint4 p = ((const uint4*)xv)[(long long)src * 16 + g];
        v[0] = bf2f((unsigned short)(p.x & 0xFFFF)); v[1] = bf2f((unsigned short)(p.x >> 16));
        v[2] = bf2f((unsigned short)(p.y & 0xFFFF)); v[3] = bf2f((unsigned short)(p.y >> 16));
        v[4] = bf2f((unsigned short)(p.z & 0xFFFF)); v[5] = bf2f((unsigned short)(p.z >> 16));
        v[6] = bf2f((unsigned short)(p.w & 0xFFFF)); v[7] = bf2f((unsigned short)(p.w >> 16));
    }
    float* a = agg + (long long)dst * FDIM + g * 8;
    #pragma unroll
    for (int j = 0; j < 8; ++j) atomicAdd(a + j, v[j]);
    if (g == 0) atomicAdd(deg + dst, 1.0f);
}

// ---------------------------------------------------------------------------
// MFMA GEMM (bf16 path): h = relu([mean|x] @ [Wl;Wr]^T + bl) -> out bf16,
// + BN column stats.
// ---------------------------------------------------------------------------
__global__ __launch_bounds__(256) void mfma_gemm_kernel(
    const unsigned short* __restrict__ mean_bf,
    const unsigned short* __restrict__ x,
    const unsigned short* __restrict__ Wl,
    const unsigned short* __restrict__ Wr,
    const float* __restrict__ bl32,
    unsigned short* __restrict__ out,
    float* __restrict__ col_sum,                  // [128] sums, then [128] sqs
    const int* __restrict__ flags, int N)
{
    if (flags[1]) return;
    __shared__ unsigned short Wc[FDIM * LDS_STRIDE];

    for (int i = threadIdx.x; i < FDIM * 32; i += 256) {
        int row = i >> 5;
        int g8  = i & 31;
        const uint4* srcp = (g8 < 16) ? (const uint4*)(Wl + row * FDIM + g8 * 8)
                                      : (const uint4*)(Wr + row * FDIM + (g8 - 16) * 8);
        *(uint4*)(Wc + row * LDS_STRIDE + g8 * 8) = *srcp;
    }
    __syncthreads();

    int wave = threadIdx.x >> 6;
    int lane = threadIdx.x & 63;
    int m    = lane & 15;
    int quad = lane >> 4;

    float bias[8];
    #pragma unroll
    for (int c = 0; c < 8; ++c) bias[c] = bl32[c * 16 + m];

    float lsum[8] = {0,0,0,0,0,0,0,0};
    float lsq[8]  = {0,0,0,0,0,0,0,0};

    int nst = (N + 31) >> 5;
    for (int st = blockIdx.x * 4 + wave; st < nst; st += gridDim.x * 4) {
        int r0 = st * 32;
        v4f acc[8][2];
        #pragma unroll
        for (int c = 0; c < 8; ++c) {
            acc[c][0] = (v4f){0.f, 0.f, 0.f, 0.f};
            acc[c][1] = (v4f){0.f, 0.f, 0.f, 0.f};
        }
        int ra = r0 + m;      if (ra > N - 1) ra = N - 1;
        int rb = r0 + 16 + m; if (rb > N - 1) rb = N - 1;
        #pragma unroll
        for (int kk = 0; kk < 8; ++kk) {
            const unsigned short* base = (kk < 4) ? mean_bf : x;
            int koff = (kk & 3) * 32 + quad * 8;
            v8s a0 = *(const v8s*)(base + (long long)ra * FDIM + koff);
            v8s a1 = *(const v8s*)(base + (long long)rb * FDIM + koff);
            #pragma unroll
            for (int c = 0; c < 8; ++c) {
                v8s b = *(const v8s*)(Wc + (c * 16 + m) * LDS_STRIDE + kk * 32 + quad * 8);
                acc[c][0] = __builtin_amdgcn_mfma_f32_16x16x32_bf16(a0, b, acc[c][0], 0, 0, 0);
                acc[c][1] = __builtin_amdgcn_mfma_f32_16x16x32_bf16(a1, b, acc[c][1], 0, 0, 0);
            }
        }
        #pragma unroll
        for (int c = 0; c < 8; ++c) {
            #pragma unroll
            for (int t = 0; t < 2; ++t) {
                #pragma unroll
                for (int reg = 0; reg < 4; ++reg) {
                    int row = r0 + t * 16 + quad * 4 + reg;
                    if (row < N) {
                        float v = acc[c][t][reg] + bias[c];
                        v = fmaxf(v, 0.0f);
                        out[(long long)row * FDIM + c * 16 + m] = f2bf(v);
                        lsum[c] += v;
                        lsq[c]  += v * v;
                    }
                }
            }
        }
    }

    __syncthreads();
    float* red = (float*)Wc;
    red[threadIdx.x] = 0.0f;
    __syncthreads();
    #pragma unroll
    for (int c = 0; c < 8; ++c) {
        atomicAdd(&red[c * 16 + m],       lsum[c]);
        atomicAdd(&red[128 + c * 16 + m], lsq[c]);
    }
    __syncthreads();
    atomicAdd(&col_sum[threadIdx.x], red[threadIdx.x]);
}

// ---------------------------------------------------------------------------
// Vector GEMM. run_mode 0: only if f32 inputs (CSR path). 1: always (fallback).
// ---------------------------------------------------------------------------
__global__ __launch_bounds__(512) void gemm_kernel(
    const float* __restrict__ agg, const float* __restrict__ deg,
    const void* __restrict__ xv,
    const float* __restrict__ Wl32, const float* __restrict__ bl32,
    const float* __restrict__ Wr32,
    void* __restrict__ out,
    float* __restrict__ col_sum, float* __restrict__ col_sq,
    const int* __restrict__ flags, int nodes, int mean_ready, int run_mode)
{
    if (run_mode == 0 && !flags[1]) return;
    __shared__ float mrow[4][FDIM];
    __shared__ float xrow[4][FDIM];
    int tid  = threadIdx.x;
    int slot = tid >> 7;
    int d    = tid & 127;
    int f32  = flags[1];
    float lsum = 0.0f, lsq = 0.0f;
    int ngroups = (nodes + 3) >> 2;
    for (int g = blockIdx.x; g < ngroups; g += gridDim.x) {
        int n = g * 4 + slot;
        __syncthreads();
        if (n < nodes) {
            float inv = mean_ready ? 1.0f : 1.0f / fmaxf(deg[n], 1.0f);
            mrow[slot][d] = agg[(long long)n * FDIM + d] * inv;
            xrow[slot][d] = f32 ? ((const float*)xv)[(long long)n * FDIM + d]
                                : bf2f(((const unsigned short*)xv)[(long long)n * FDIM + d]);
        }
        __syncthreads();
        if (n < nodes) {
            float acc = bl32[d];
            const float4* wl4 = (const float4*)(Wl32 + d * FDIM);
            const float4* wr4 = (const float4*)(Wr32 + d * FDIM);
            const float* mr = mrow[slot];
            const float* xr = xrow[slot];
            #pragma unroll
            for (int c = 0; c < 32; ++c) {
                float4 wa = wl4[c];
                float4 wb = wr4[c];
                int k = c * 4;
                acc += wa.x * mr[k] + wa.y * mr[k + 1] + wa.z * mr[k + 2] + wa.w * mr[k + 3];
                acc += wb.x * xr[k] + wb.y * xr[k + 1] + wb.z * xr[k + 2] + wb.w * xr[k + 3];
            }
            acc = fmaxf(acc, 0.0f);
            if (f32) ((float*)out)[(long long)n * FDIM + d] = acc;
            else     ((unsigned short*)out)[(long long)n * FDIM + d] = f2bf(acc);
            lsum += acc;
            lsq  += acc * acc;
        }
    }
    __syncthreads();
    mrow[slot][d] = lsum;
    xrow[slot][d] = lsq;
    __syncthreads();
    if (slot == 0) {
        atomicAdd(&col_sum[d], mrow[0][d] + mrow[1][d] + mrow[2][d] + mrow[3][d]);
        atomicAdd(&col_sq[d],  xrow[0][d] + xrow[1][d] + xrow[2][d] + xrow[3][d]);
    }
}

// ---------------------------------------------------------------------------
__global__ void bn_prep(const float* __restrict__ col_sum, const float* __restrict__ col_sq,
                        const float* __restrict__ gm32, const float* __restrict__ bt32,
                        float* __restrict__ scale, float* __restrict__ shift, int nodes)
{
    int d = threadIdx.x;
    float invN = 1.0f / (float)nodes;
    float mu  = col_sum[d] * invN;
    float var = col_sq[d] * invN - mu * mu;
    float sc  = gm32[d] * rsqrtf(var + BN_EPS);
    scale[d] = sc;
    shift[d] = bt32[d] - mu * sc;
}

// ---------------------------------------------------------------------------
__global__ __launch_bounds__(256) void ChemSageBlock_89206470738295_kernel(
    void* __restrict__ hv,
    const float* __restrict__ scale, const float* __restrict__ shift,
    const int* __restrict__ flags, long long nd)
{
    long long idx = (long long)blockIdx.x * 256 + threadIdx.x;
    if (flags[1]) {
        long long tot = nd >> 2;
        if (idx >= tot) return;
        int d0 = (int)(idx & 31) * 4;
        float4 p = ((float4*)hv)[idx];
        p.x = p.x * scale[d0 + 0] + shift[d0 + 0];
        p.y = p.y * scale[d0 + 1] + shift[d0 + 1];
        p.z = p.z * scale[d0 + 2] + shift[d0 + 2];
        p.w = p.w * scale[d0 + 3] + shift[d0 + 3];
        ((float4*)hv)[idx] = p;
    } else {
        long long tot = nd >> 3;
        if (idx >= tot) return;
        int d0 = (int)(idx & 15) * 8;
        uint4 p = ((uint4*)hv)[idx];
        unsigned int q[4] = {p.x, p.y, p.z, p.w};
        #pragma unroll
        for (int j = 0; j < 4; ++j) {
            int dd = d0 + j * 2;
            float lo = bf2f((unsigned short)(q[j] & 0xFFFF));
            float hi = bf2f((unsigned short)(q[j] >> 16));
            lo = lo * scale[dd]     + shift[dd];
            hi = hi * scale[dd + 1] + shift[dd + 1];
            q[j] = (unsigned int)f2bf(lo) | ((unsigned int)f2bf(hi) << 16);
        }
        uint4 r; r.x = q[0]; r.y = q[1]; r.z = q[2]; r.w = q[3];
        ((uint4*)hv)[idx] = r;
    }
}

// ---------------------------------------------------------------------------
extern "C" __attribute__((visibility("default")))
void kernel_launch(void* const* d_in, const int* in_sizes, int n_in,
                   void* d_out, int out_size, void* d_ws, size_t ws_size,
                   hipStream_t stream)
{
    int N = 100000, E = 1600000;
    if (in_sizes) {
        if (in_sizes[0] > 0 && (in_sizes[0] % FDIM) == 0) N = in_sizes[0] / FDIM;
        if (in_sizes[1] > 0 && (in_sizes[1] % 2) == 0)    E = in_sizes[1] / 2;
    }
    const void* x  = d_in[0];
    const int*  ei = (const int*)d_in[1];
    const void* Wl = d_in[2];
    const void* bl = d_in[3];
    const void* Wr = d_in[4];
    const void* gm = d_in[5];
    const void* bt = d_in[6];

    float* agg     = (float*)d_ws;
    float* Wl32    = agg + (size_t)N * FDIM;
    float* Wr32    = Wl32 + FDIM * FDIM;
    float* bl32    = Wr32 + FDIM * FDIM;
    float* gm32    = bl32 + FDIM;
    float* bt32    = gm32 + FDIM;
    float* scale   = bt32 + FDIM;
    float* shift   = scale + FDIM;
    float* col_sum = shift + FDIM;
    float* col_sq  = col_sum + FDIM;
    int*   cnt     = (int*)(col_sq + FDIM);
    int*   cursor  = cnt + N;
    int*   row_st  = cursor + N;
    int*   csr_src = row_st + N + 64;
    int*   flags   = csr_src + E;
    size_t ws_need = (size_t)(flags + 16 - (int*)d_ws) * 4;
    unsigned short* mean_bf = (unsigned short*)agg;

    detect_convert_kernel<<<1, 256, 0, stream>>>(
        (const unsigned int*)x, ei, Wl, bl, Wr, gm, bt,
        Wl32, Wr32, bl32, gm32, bt32, flags);

    int eblocks = (E + 255) / 256;
    if (ws_size >= ws_need) {
        long long zcount = 2 * FDIM + 2 * (long long)N;
        zero_kernel<<<512, 256, 0, stream>>>(col_sum, zcount);
        count_kernel<<<eblocks, 256, 0, stream>>>(ei, cnt, flags, E, N);
        scan_kernel<<<1, 1024, 0, stream>>>(cnt, row_st, N);
        fill_kernel<<<eblocks, 256, 0, stream>>>(ei, row_st, cursor, csr_src, flags, E, N);
        aggregate_kernel<<<(N + 3) / 4, 256, 0, stream>>>(
            x, csr_src, row_st, agg, mean_bf, flags, N);
        mfma_gemm_kernel<<<512, 256, 0, stream>>>(
            mean_bf, (const unsigned short*)x, (const unsigned short*)Wl,
            (const unsigned short*)Wr, bl32, (unsigned short*)d_out,
            col_sum, flags, N);
        gemm_kernel<<<2048, 512, 0, stream>>>(agg, nullptr, x, Wl32, bl32, Wr32,
                                              d_out, col_sum, col_sq, flags, N, 1, 0);
    } else {
        long long zcount = (long long)N * FDIM;
        zero_kernel<<<2048, 256, 0, stream>>>(agg, zcount);
        zero_kernel<<<512, 256, 0, stream>>>(col_sum, 2 * FDIM + (long long)N);
        long long sc_threads = (long long)E * 16;
        scatter_kernel<<<(int)((sc_threads + 255) / 256), 256, 0, stream>>>(
            x, ei, agg, (float*)cnt, flags, E, N);
        gemm_kernel<<<2048, 512, 0, stream>>>(agg, (const float*)cnt, x, Wl32, bl32, Wr32,
                                              d_out, col_sum, col_sq, flags, N, 0, 1);
    }

    bn_prep<<<1, 128, 0, stream>>>(col_sum, col_sq, gm32, bt32, scale, shift, N);

    long long nd = (long long)N * FDIM;
    ChemSageBlock_89206470738295_kernel<<<(int)((nd / 4 + 255) / 256), 256, 0, stream>>>(
        d_out, scale, shift, flags, nd);
}

// Round 6
// 586.884 us; speedup vs baseline: 12.3056x; 3.3726x over previous
//
#include <hip/hip_runtime.h>

#define FDIM 128
#define BN_EPS 1e-5f
#define LDS_STRIDE 264   // 256 + 8 bf16 pad for LDS b128 reads

typedef short v8s __attribute__((ext_vector_type(8)));
typedef float v4f __attribute__((ext_vector_type(4)));

__device__ __forceinline__ float bf2f(unsigned short u) {
    union { unsigned int i; float f; } v; v.i = ((unsigned int)u) << 16; return v.f;
}
__device__ __forceinline__ unsigned short f2bf(float f) {
    union { float f2; unsigned int i; } v; v.f2 = f;
    unsigned int r = v.i + 0x7FFFu + ((v.i >> 16) & 1u);  // RNE
    return (unsigned short)(r >> 16);
}

// ---------------------------------------------------------------------------
// Detect dtypes; build Wc (bf16 [128 rows][256 k], k<128=Wl, k>=128=Wr),
// Wl32/Wr32 (f32, fallback), and f32 param vectors.
// flags[0]=ei_is_int64, flags[1]=floats_are_f32.
// ---------------------------------------------------------------------------
__global__ void detect_convert_kernel(
    const unsigned int* __restrict__ xw, const int* __restrict__ ei,
    const void* __restrict__ Wl, const void* __restrict__ bl,
    const void* __restrict__ Wr, const void* __restrict__ gm,
    const void* __restrict__ bt,
    unsigned short* __restrict__ Wc,
    float* __restrict__ Wl32, float* __restrict__ Wr32,
    float* __restrict__ bl32, float* __restrict__ gm32, float* __restrict__ bt32,
    int* __restrict__ flags)
{
    __shared__ int s_f32;
    if (threadIdx.x == 0) {
        int any = 0;
        for (int k = 0; k < 128; ++k) any |= ei[2 * k + 1];
        flags[0] = (any == 0) ? 1 : 0;
        // bf16-vs-f32: low halfwords of f32 words are random mantissa bits,
        // implausible as bf16 N(0,1) exponents.
        int cnt = 0;
        for (int k = 0; k < 128; ++k) {
            unsigned short h = (unsigned short)(xw[k] & 0xFFFFu);
            int e = (h >> 7) & 0xFF;
            cnt += (h == 0 || (e >= 116 && e <= 133)) ? 1 : 0;
        }
        int f32 = (cnt < 64) ? 1 : 0;
        flags[1] = f32;
        s_f32 = f32;
    }
    __syncthreads();
    int f32 = s_f32;
    for (int i = threadIdx.x; i < FDIM * FDIM; i += blockDim.x) {
        int d = i >> 7, k = i & 127;
        float wl = f32 ? ((const float*)Wl)[i] : bf2f(((const unsigned short*)Wl)[i]);
        float wr = f32 ? ((const float*)Wr)[i] : bf2f(((const unsigned short*)Wr)[i]);
        Wl32[i] = wl;
        Wr32[i] = wr;
        Wc[d * 256 + k]       = f2bf(wl);
        Wc[d * 256 + 128 + k] = f2bf(wr);
    }
    for (int i = threadIdx.x; i < FDIM; i += blockDim.x) {
        bl32[i] = f32 ? ((const float*)bl)[i] : bf2f(((const unsigned short*)bl)[i]);
        gm32[i] = f32 ? ((const float*)gm)[i] : bf2f(((const unsigned short*)gm)[i]);
        bt32[i] = f32 ? ((const float*)bt)[i] : bf2f(((const unsigned short*)bt)[i]);
    }
}

// ---------------------------------------------------------------------------
// x -> bf16 copy (8 elems / thread).
// ---------------------------------------------------------------------------
__global__ __launch_bounds__(256) void convert_x_kernel(
    const void* __restrict__ xv, unsigned short* __restrict__ x_bf,
    const int* __restrict__ flags, long long n8)
{
    long long i = (long long)blockIdx.x * 256 + threadIdx.x;
    if (i >= n8) return;
    if (flags[1]) {
        const float4* xf = (const float4*)xv;
        float4 a = xf[i * 2], b = xf[i * 2 + 1];
        uint4 p;
        p.x = (unsigned int)f2bf(a.x) | ((unsigned int)f2bf(a.y) << 16);
        p.y = (unsigned int)f2bf(a.z) | ((unsigned int)f2bf(a.w) << 16);
        p.z = (unsigned int)f2bf(b.x) | ((unsigned int)f2bf(b.y) << 16);
        p.w = (unsigned int)f2bf(b.z) | ((unsigned int)f2bf(b.w) << 16);
        ((uint4*)x_bf)[i] = p;
    } else {
        ((uint4*)x_bf)[i] = ((const uint4*)xv)[i];
    }
}

// ---------------------------------------------------------------------------
__global__ __launch_bounds__(256) void zero_kernel(float* __restrict__ z, long long n)
{
    long long i = (long long)blockIdx.x * 256 + threadIdx.x;
    long long stride = (long long)gridDim.x * 256;
    for (; i < n; i += stride) z[i] = 0.0f;
}

__device__ __forceinline__ int edge_at(const int* ei, long long pos, int is64) {
    return is64 ? ei[2 * pos] : ei[pos];
}

// ---------------------------------------------------------------------------
// CSR phase 1: in-degree counts (same validity predicate as fill).
// ---------------------------------------------------------------------------
__global__ __launch_bounds__(256) void count_kernel(
    const int* __restrict__ ei, int* __restrict__ cnt,
    const int* __restrict__ flags, int E, int N)
{
    int e = blockIdx.x * 256 + threadIdx.x;
    if (e >= E) return;
    int is64 = flags[0];
    int src = edge_at(ei, e, is64);
    int dst = edge_at(ei, (long long)E + e, is64);
    if ((unsigned)src >= (unsigned)N || (unsigned)dst >= (unsigned)N) return;
    atomicAdd(&cnt[dst], 1);
}

// ---------------------------------------------------------------------------
// CSR phase 2: exclusive scan (single block).
// ---------------------------------------------------------------------------
__global__ __launch_bounds__(1024) void scan_kernel(
    const int* __restrict__ cnt, int* __restrict__ row_start, int N)
{
    __shared__ int part[1024];
    int t = threadIdx.x;
    int chunk = (N + 1023) / 1024;
    int lo = t * chunk; if (lo > N) lo = N;
    int hi = lo + chunk; if (hi > N) hi = N;
    int s = 0;
    for (int i = lo; i < hi; ++i) s += cnt[i];
    part[t] = s;
    __syncthreads();
    for (int off = 1; off < 1024; off <<= 1) {
        int v = (t >= off) ? part[t - off] : 0;
        __syncthreads();
        part[t] += v;
        __syncthreads();
    }
    int run = (t == 0) ? 0 : part[t - 1];
    for (int i = lo; i < hi; ++i) { row_start[i] = run; run += cnt[i]; }
    if (hi == N) row_start[N] = run;
}

// ---------------------------------------------------------------------------
// CSR phase 3: bucket-fill sources.
// ---------------------------------------------------------------------------
__global__ __launch_bounds__(256) void fill_kernel(
    const int* __restrict__ ei, const int* __restrict__ row_start,
    int* __restrict__ cursor, int* __restrict__ csr_src,
    const int* __restrict__ flags, int E, int N)
{
    int e = blockIdx.x * 256 + threadIdx.x;
    if (e >= E) return;
    int is64 = flags[0];
    int src = edge_at(ei, e, is64);
    int dst = edge_at(ei, (long long)E + e, is64);
    if ((unsigned)src >= (unsigned)N || (unsigned)dst >= (unsigned)N) return;
    int pos = atomicAdd(&cursor[dst], 1);
    csr_src[row_start[dst] + pos] = src;
}

// ---------------------------------------------------------------------------
// CSR phase 4: gather bf16 x rows, mean -> bf16. One wave per node:
// 4 edge-slots x 16 feature-groups (8 bf16 each).
// ---------------------------------------------------------------------------
__global__ __launch_bounds__(256) void aggregate_kernel(
    const unsigned short* __restrict__ x_bf, const int* __restrict__ csr_src,
    const int* __restrict__ row_start, unsigned short* __restrict__ mean_bf, int N)
{
    int wave = threadIdx.x >> 6;
    int lane = threadIdx.x & 63;
    int n = blockIdx.x * 4 + wave;
    if (n >= N) return;
    int g = lane & 15, slot = lane >> 4;
    int start = row_start[n], end = row_start[n + 1];
    float acc[8] = {0, 0, 0, 0, 0, 0, 0, 0};
    for (int i = start + slot; i < end; i += 4) {
        int src = csr_src[i];
        uint4 p = ((const uint4*)x_bf)[(long long)src * 16 + g];
        acc[0] += bf2f((unsigned short)(p.x & 0xFFFF));
        acc[1] += bf2f((unsigned short)(p.x >> 16));
        acc[2] += bf2f((unsigned short)(p.y & 0xFFFF));
        acc[3] += bf2f((unsigned short)(p.y >> 16));
        acc[4] += bf2f((unsigned short)(p.z & 0xFFFF));
        acc[5] += bf2f((unsigned short)(p.z >> 16));
        acc[6] += bf2f((unsigned short)(p.w & 0xFFFF));
        acc[7] += bf2f((unsigned short)(p.w >> 16));
    }
    #pragma unroll
    for (int j = 0; j < 8; ++j) {
        acc[j] += __shfl_xor(acc[j], 16, 64);
        acc[j] += __shfl_xor(acc[j], 32, 64);
    }
    if (slot == 0) {
        float inv = 1.0f / fmaxf((float)(end - start), 1.0f);
        uint4 p;
        p.x = (unsigned int)f2bf(acc[0] * inv) | ((unsigned int)f2bf(acc[1] * inv) << 16);
        p.y = (unsigned int)f2bf(acc[2] * inv) | ((unsigned int)f2bf(acc[3] * inv) << 16);
        p.z = (unsigned int)f2bf(acc[4] * inv) | ((unsigned int)f2bf(acc[5] * inv) << 16);
        p.w = (unsigned int)f2bf(acc[6] * inv) | ((unsigned int)f2bf(acc[7] * inv) << 16);
        ((uint4*)(mean_bf + (long long)n * FDIM + g * 8))[0] = p;
    }
}

// ---------------------------------------------------------------------------
// MFMA GEMM: h = relu([mean|x]_bf16 @ Wc^T + bl) -> out (f32 or bf16 per
// flags[1]) + BN column stats. Block = 4 waves; Wc staged in LDS.
// Wave supertile: 32 rows x 128 cols. mfma_f32_16x16x32_bf16.
// A-frag: A[m=lane&15][k=quad*8+j]; C/D: col=lane&15, row=quad*4+reg (m89/m92).
// ---------------------------------------------------------------------------
__global__ __launch_bounds__(256) void mfma_gemm_kernel(
    const unsigned short* __restrict__ mean_bf,
    const unsigned short* __restrict__ x_bf,
    const unsigned short* __restrict__ Wc_ws,   // [128][256] bf16
    const float* __restrict__ bl32,
    void* __restrict__ out,
    float* __restrict__ col_sum,                // [128] sums then [128] sqs
    const int* __restrict__ flags, int N)
{
    __shared__ unsigned short Wc[FDIM * LDS_STRIDE];
    int f32out = flags[1];

    for (int i = threadIdx.x; i < FDIM * 32; i += 256) {     // 32 uint4 per row
        int row = i >> 5;
        int g8  = i & 31;
        *(uint4*)(Wc + row * LDS_STRIDE + g8 * 8) =
            *(const uint4*)(Wc_ws + row * 256 + g8 * 8);
    }
    __syncthreads();

    int wave = threadIdx.x >> 6;
    int lane = threadIdx.x & 63;
    int m    = lane & 15;
    int quad = lane >> 4;

    float bias[8];
    #pragma unroll
    for (int c = 0; c < 8; ++c) bias[c] = bl32[c * 16 + m];

    float lsum[8] = {0,0,0,0,0,0,0,0};
    float lsq[8]  = {0,0,0,0,0,0,0,0};

    int nst = (N + 31) >> 5;
    for (int st = blockIdx.x * 4 + wave; st < nst; st += gridDim.x * 4) {
        int r0 = st * 32;
        v4f acc[8][2];
        #pragma unroll
        for (int c = 0; c < 8; ++c) {
            acc[c][0] = (v4f){0.f, 0.f, 0.f, 0.f};
            acc[c][1] = (v4f){0.f, 0.f, 0.f, 0.f};
        }
        int ra = r0 + m;      if (ra > N - 1) ra = N - 1;
        int rb = r0 + 16 + m; if (rb > N - 1) rb = N - 1;
        #pragma unroll
        for (int kk = 0; kk < 8; ++kk) {
            const unsigned short* base = (kk < 4) ? mean_bf : x_bf;
            int koff = (kk & 3) * 32 + quad * 8;
            v8s a0 = *(const v8s*)(base + (long long)ra * FDIM + koff);
            v8s a1 = *(const v8s*)(base + (long long)rb * FDIM + koff);
            #pragma unroll
            for (int c = 0; c < 8; ++c) {
                v8s b = *(const v8s*)(Wc + (c * 16 + m) * LDS_STRIDE + kk * 32 + quad * 8);
                acc[c][0] = __builtin_amdgcn_mfma_f32_16x16x32_bf16(a0, b, acc[c][0], 0, 0, 0);
                acc[c][1] = __builtin_amdgcn_mfma_f32_16x16x32_bf16(a1, b, acc[c][1], 0, 0, 0);
            }
        }
        #pragma unroll
        for (int c = 0; c < 8; ++c) {
            #pragma unroll
            for (int t = 0; t < 2; ++t) {
                #pragma unroll
                for (int reg = 0; reg < 4; ++reg) {
                    int row = r0 + t * 16 + quad * 4 + reg;
                    if (row < N) {
                        float v = acc[c][t][reg] + bias[c];
                        v = fmaxf(v, 0.0f);
                        if (f32out) ((float*)out)[(long long)row * FDIM + c * 16 + m] = v;
                        else ((unsigned short*)out)[(long long)row * FDIM + c * 16 + m] = f2bf(v);
                        lsum[c] += v;
                        lsq[c]  += v * v;
                    }
                }
            }
        }
    }

    __syncthreads();
    float* red = (float*)Wc;
    red[threadIdx.x] = 0.0f;
    __syncthreads();
    #pragma unroll
    for (int c = 0; c < 8; ++c) {
        atomicAdd(&red[c * 16 + m],       lsum[c]);
        atomicAdd(&red[128 + c * 16 + m], lsq[c]);
    }
    __syncthreads();
    atomicAdd(&col_sum[threadIdx.x], red[threadIdx.x]);
}

// ---------------------------------------------------------------------------
// Fallback scatter + vector GEMM (only if ws too small for CSR).
// ---------------------------------------------------------------------------
__global__ __launch_bounds__(256) void scatter_kernel(
    const void* __restrict__ xv, const int* __restrict__ ei,
    float* __restrict__ agg, float* __restrict__ deg,
    const int* __restrict__ flags, int E, int N)
{
    long long idx = (long long)blockIdx.x * 256 + threadIdx.x;
    if (idx >= (long long)E * 16) return;
    int e = (int)(idx >> 4);
    int g = (int)(idx & 15);
    int is64 = flags[0];
    int src = edge_at(ei, e, is64);
    int dst = edge_at(ei, (long long)E + e, is64);
    if ((unsigned)src >= (unsigned)N || (unsigned)dst >= (unsigned)N) return;
    float v[8];
    if (flags[1]) {
        const float4* xr = (const float4*)xv;
        float4 a = xr[(long long)src * 32 + g * 2];
        float4 b = xr[(long long)src * 32 + g * 2 + 1];
        v[0] = a.x; v[1] = a.y; v[2] = a.z; v[3] = a.w;
        v[4] = b.x; v[5] = b.y; v[6] = b.z; v[7] = b.w;
    } else {
        uint4 p = ((const uint4*)xv)[(long long)src * 16 + g];
        v[0] = bf2f((unsigned short)(p.x & 0xFFFF)); v[1] = bf2f((unsigned short)(p.x >> 16));
        v[2] = bf2f((unsigned short)(p.y & 0xFFFF)); v[3] = bf2f((unsigned short)(p.y >> 16));
        v[4] = bf2f((unsigned short)(p.z & 0xFFFF)); v[5] = bf2f((unsigned short)(p.z >> 16));
        v[6] = bf2f((unsigned short)(p.w & 0xFFFF)); v[7] = bf2f((unsigned short)(p.w >> 16));
    }
    float* a = agg + (long long)dst * FDIM + g * 8;
    #pragma unroll
    for (int j = 0; j < 8; ++j) atomicAdd(a + j, v[j]);
    if (g == 0) atomicAdd(deg + dst, 1.0f);
}

__global__ __launch_bounds__(512) void gemm_kernel(
    const float* __restrict__ agg, const float* __restrict__ deg,
    const void* __restrict__ xv,
    const float* __restrict__ Wl32, const float* __restrict__ bl32,
    const float* __restrict__ Wr32,
    void* __restrict__ out,
    float* __restrict__ col_sum, float* __restrict__ col_sq,
    const int* __restrict__ flags, int nodes)
{
    __shared__ float mrow[4][FDIM];
    __shared__ float xrow[4][FDIM];
    int tid  = threadIdx.x;
    int slot = tid >> 7;
    int d    = tid & 127;
    int f32  = flags[1];
    float lsum = 0.0f, lsq = 0.0f;
    int ngroups = (nodes + 3) >> 2;
    for (int g = blockIdx.x; g < ngroups; g += gridDim.x) {
        int n = g * 4 + slot;
        __syncthreads();
        if (n < nodes) {
            float inv = 1.0f / fmaxf(deg[n], 1.0f);
            mrow[slot][d] = agg[(long long)n * FDIM + d] * inv;
            xrow[slot][d] = f32 ? ((const float*)xv)[(long long)n * FDIM + d]
                                : bf2f(((const unsigned short*)xv)[(long long)n * FDIM + d]);
        }
        __syncthreads();
        if (n < nodes) {
            float acc = bl32[d];
            const float4* wl4 = (const float4*)(Wl32 + d * FDIM);
            const float4* wr4 = (const float4*)(Wr32 + d * FDIM);
            const float* mr = mrow[slot];
            const float* xr = xrow[slot];
            #pragma unroll
            for (int c = 0; c < 32; ++c) {
                float4 wa = wl4[c];
                float4 wb = wr4[c];
                int k = c * 4;
                acc += wa.x * mr[k] + wa.y * mr[k + 1] + wa.z * mr[k + 2] + wa.w * mr[k + 3];
                acc += wb.x * xr[k] + wb.y * xr[k + 1] + wb.z * xr[k + 2] + wb.w * xr[k + 3];
            }
            acc = fmaxf(acc, 0.0f);
            if (f32) ((float*)out)[(long long)n * FDIM + d] = acc;
            else     ((unsigned short*)out)[(long long)n * FDIM + d] = f2bf(acc);
            lsum += acc;
            lsq  += acc * acc;
        }
    }
    __syncthreads();
    mrow[slot][d] = lsum;
    xrow[slot][d] = lsq;
    __syncthreads();
    if (slot == 0) {
        atomicAdd(&col_sum[d], mrow[0][d] + mrow[1][d] + mrow[2][d] + mrow[3][d]);
        atomicAdd(&col_sq[d],  xrow[0][d] + xrow[1][d] + xrow[2][d] + xrow[3][d]);
    }
}

// ---------------------------------------------------------------------------
__global__ void bn_prep(const float* __restrict__ col_sum, const float* __restrict__ col_sq,
                        const float* __restrict__ gm32, const float* __restrict__ bt32,
                        float* __restrict__ scale, float* __restrict__ shift, int nodes)
{
    int d = threadIdx.x;
    float invN = 1.0f / (float)nodes;
    float mu  = col_sum[d] * invN;
    float var = col_sq[d] * invN - mu * mu;
    float sc  = gm32[d] * rsqrtf(var + BN_EPS);
    scale[d] = sc;
    shift[d] = bt32[d] - mu * sc;
}

// ---------------------------------------------------------------------------
__global__ __launch_bounds__(256) void ChemSageBlock_89206470738295_kernel(
    void* __restrict__ hv,
    const float* __restrict__ scale, const float* __restrict__ shift,
    const int* __restrict__ flags, long long nd)
{
    long long idx = (long long)blockIdx.x * 256 + threadIdx.x;
    if (flags[1]) {
        long long tot = nd >> 2;
        if (idx >= tot) return;
        int d0 = (int)(idx & 31) * 4;
        float4 p = ((float4*)hv)[idx];
        p.x = p.x * scale[d0 + 0] + shift[d0 + 0];
        p.y = p.y * scale[d0 + 1] + shift[d0 + 1];
        p.z = p.z * scale[d0 + 2] + shift[d0 + 2];
        p.w = p.w * scale[d0 + 3] + shift[d0 + 3];
        ((float4*)hv)[idx] = p;
    } else {
        long long tot = nd >> 3;
        if (idx >= tot) return;
        int d0 = (int)(idx & 15) * 8;
        uint4 p = ((uint4*)hv)[idx];
        unsigned int q[4] = {p.x, p.y, p.z, p.w};
        #pragma unroll
        for (int j = 0; j < 4; ++j) {
            int dd = d0 + j * 2;
            float lo = bf2f((unsigned short)(q[j] & 0xFFFF));
            float hi = bf2f((unsigned short)(q[j] >> 16));
            lo = lo * scale[dd]     + shift[dd];
            hi = hi * scale[dd + 1] + shift[dd + 1];
            q[j] = (unsigned int)f2bf(lo) | ((unsigned int)f2bf(hi) << 16);
        }
        uint4 r; r.x = q[0]; r.y = q[1]; r.z = q[2]; r.w = q[3];
        ((uint4*)hv)[idx] = r;
    }
}

// ---------------------------------------------------------------------------
extern "C" __attribute__((visibility("default")))
void kernel_launch(void* const* d_in, const int* in_sizes, int n_in,
                   void* d_out, int out_size, void* d_ws, size_t ws_size,
                   hipStream_t stream)
{
    int N = 100000, E = 1600000;
    if (in_sizes) {
        if (in_sizes[0] > 0 && (in_sizes[0] % FDIM) == 0) N = in_sizes[0] / FDIM;
        if (in_sizes[1] > 0 && (in_sizes[1] % 2) == 0)    E = in_sizes[1] / 2;
    }
    const void* x  = d_in[0];
    const int*  ei = (const int*)d_in[1];
    const void* Wl = d_in[2];
    const void* bl = d_in[3];
    const void* Wr = d_in[4];
    const void* gm = d_in[5];
    const void* bt = d_in[6];

    // ws layout:
    // x_bf[N*128] u16 | mean_bf[N*128] u16 | Wc[128*256] u16 |
    // Wl32,Wr32[16384 f32 ea] | bl32,gm32,bt32,scale,shift[128 f32 ea] |
    // col_sum,col_sq[128 f32 ea] | cnt[N] cursor[N] row_st[N+64] csr_src[E] | flags[16]
    unsigned short* x_bf    = (unsigned short*)d_ws;
    unsigned short* mean_bf = x_bf + (size_t)N * FDIM;
    unsigned short* Wc      = mean_bf + (size_t)N * FDIM;
    float* Wl32    = (float*)(Wc + FDIM * 256);
    float* Wr32    = Wl32 + FDIM * FDIM;
    float* bl32    = Wr32 + FDIM * FDIM;
    float* gm32    = bl32 + FDIM;
    float* bt32    = gm32 + FDIM;
    float* scale   = bt32 + FDIM;
    float* shift   = scale + FDIM;
    float* col_sum = shift + FDIM;
    float* col_sq  = col_sum + FDIM;
    int*   cnt     = (int*)(col_sq + FDIM);
    int*   cursor  = cnt + N;
    int*   row_st  = cursor + N;
    int*   csr_src = row_st + N + 64;
    int*   flags   = csr_src + E;
    size_t ws_need = (size_t)((char*)(flags + 16) - (char*)d_ws);

    detect_convert_kernel<<<1, 256, 0, stream>>>(
        (const unsigned int*)x, ei, Wl, bl, Wr, gm, bt,
        Wc, Wl32, Wr32, bl32, gm32, bt32, flags);

    int eblocks = (E + 255) / 256;
    long long nd = (long long)N * FDIM;

    if (ws_size >= ws_need) {
        // CSR + MFMA path
        long long n8 = nd >> 3;
        convert_x_kernel<<<(int)((n8 + 255) / 256), 256, 0, stream>>>(x, x_bf, flags, n8);
        // zero col_sum..cursor (256 floats + 2N ints, contiguous)
        zero_kernel<<<512, 256, 0, stream>>>(col_sum, 2 * FDIM + 2 * (long long)N);
        count_kernel<<<eblocks, 256, 0, stream>>>(ei, cnt, flags, E, N);
        scan_kernel<<<1, 1024, 0, stream>>>(cnt, row_st, N);
        fill_kernel<<<eblocks, 256, 0, stream>>>(ei, row_st, cursor, csr_src, flags, E, N);
        aggregate_kernel<<<(N + 3) / 4, 256, 0, stream>>>(x_bf, csr_src, row_st, mean_bf, N);
        mfma_gemm_kernel<<<512, 256, 0, stream>>>(
            mean_bf, x_bf, Wc, bl32, d_out, col_sum, flags, N);
    } else {
        // Fallback: atomic scatter + vector GEMM. agg f32 aliases x_bf+mean_bf.
        float* agg = (float*)d_ws;
        zero_kernel<<<2048, 256, 0, stream>>>(agg, nd);
        zero_kernel<<<512, 256, 0, stream>>>(col_sum, 2 * FDIM + (long long)N); // stats + cnt(deg)
        long long sc_threads = (long long)E * 16;
        scatter_kernel<<<(int)((sc_threads + 255) / 256), 256, 0, stream>>>(
            x, ei, agg, (float*)cnt, flags, E, N);
        gemm_kernel<<<2048, 512, 0, stream>>>(agg, (const float*)cnt, x, Wl32, bl32, Wr32,
                                              d_out, col_sum, col_sq, flags, N);
    }

    bn_prep<<<1, 128, 0, stream>>>(col_sum, col_sq, gm32, bt32, scale, shift, N);

    ChemSageBlock_89206470738295_kernel<<<(int)((nd / 4 + 255) / 256), 256, 0, stream>>>(
        d_out, scale, shift, flags, nd);
}

// Round 7
// 446.092 us; speedup vs baseline: 16.1893x; 1.3156x over previous
//
#include <hip/hip_runtime.h>

#define FDIM 128
#define BN_EPS 1e-5f
#define LDS_STRIDE 264   // 256 + 8 bf16 pad for LDS b128 reads

typedef short v8s __attribute__((ext_vector_type(8)));
typedef float v4f __attribute__((ext_vector_type(4)));

__device__ __forceinline__ float bf2f(unsigned short u) {
    union { unsigned int i; float f; } v; v.i = ((unsigned int)u) << 16; return v.f;
}
__device__ __forceinline__ unsigned short f2bf(float f) {
    union { float f2; unsigned int i; } v; v.f2 = f;
    unsigned int r = v.i + 0x7FFFu + ((v.i >> 16) & 1u);  // RNE
    return (unsigned short)(r >> 16);
}

// ---------------------------------------------------------------------------
// Detect dtypes; build Wc (bf16 [128 rows][256 k]), f32 params, zero cursor.
// flags[0]=ei_is_int64, flags[1]=floats_are_f32, flags[4]=global alloc cursor.
// ---------------------------------------------------------------------------
__global__ __launch_bounds__(1024) void detect_convert_kernel(
    const unsigned int* __restrict__ xw, const int* __restrict__ ei,
    const void* __restrict__ Wl, const void* __restrict__ bl,
    const void* __restrict__ Wr, const void* __restrict__ gm,
    const void* __restrict__ bt,
    unsigned short* __restrict__ Wc,
    float* __restrict__ Wl32, float* __restrict__ Wr32,
    float* __restrict__ bl32, float* __restrict__ gm32, float* __restrict__ bt32,
    int* __restrict__ flags)
{
    __shared__ int s_f32;
    if (threadIdx.x == 0) {
        int any = 0;
        for (int k = 0; k < 128; ++k) any |= ei[2 * k + 1];
        flags[0] = (any == 0) ? 1 : 0;
        // bf16-vs-f32: low halfwords of f32 words are random mantissa bits,
        // implausible as bf16 values from N(0,1).
        int cnt = 0;
        for (int k = 0; k < 128; ++k) {
            unsigned short h = (unsigned short)(xw[k] & 0xFFFFu);
            int e = (h >> 7) & 0xFF;
            cnt += (h == 0 || (e >= 116 && e <= 133)) ? 1 : 0;
        }
        int f32 = (cnt < 64) ? 1 : 0;
        flags[1] = f32;
        s_f32 = f32;
        flags[4] = 0;                        // csr allocation cursor
    }
    __syncthreads();
    int f32 = s_f32;
    for (int i = threadIdx.x; i < FDIM * FDIM; i += blockDim.x) {
        int d = i >> 7, k = i & 127;
        float wl = f32 ? ((const float*)Wl)[i] : bf2f(((const unsigned short*)Wl)[i]);
        float wr = f32 ? ((const float*)Wr)[i] : bf2f(((const unsigned short*)Wr)[i]);
        Wl32[i] = wl;
        Wr32[i] = wr;
        Wc[d * 256 + k]       = f2bf(wl);
        Wc[d * 256 + 128 + k] = f2bf(wr);
    }
    if (threadIdx.x < FDIM) {
        int i = threadIdx.x;
        bl32[i] = f32 ? ((const float*)bl)[i] : bf2f(((const unsigned short*)bl)[i]);
        gm32[i] = f32 ? ((const float*)gm)[i] : bf2f(((const unsigned short*)gm)[i]);
        bt32[i] = f32 ? ((const float*)bt)[i] : bf2f(((const unsigned short*)bt)[i]);
    }
}

// ---------------------------------------------------------------------------
// x -> bf16 copy (8 elems / thread).
// ---------------------------------------------------------------------------
__global__ __launch_bounds__(256) void convert_x_kernel(
    const void* __restrict__ xv, unsigned short* __restrict__ x_bf,
    const int* __restrict__ flags, long long n8)
{
    long long i = (long long)blockIdx.x * 256 + threadIdx.x;
    if (i >= n8) return;
    if (flags[1]) {
        const float4* xf = (const float4*)xv;
        float4 a = xf[i * 2], b = xf[i * 2 + 1];
        uint4 p;
        p.x = (unsigned int)f2bf(a.x) | ((unsigned int)f2bf(a.y) << 16);
        p.y = (unsigned int)f2bf(a.z) | ((unsigned int)f2bf(a.w) << 16);
        p.z = (unsigned int)f2bf(b.x) | ((unsigned int)f2bf(b.y) << 16);
        p.w = (unsigned int)f2bf(b.z) | ((unsigned int)f2bf(b.w) << 16);
        ((uint4*)x_bf)[i] = p;
    } else {
        ((uint4*)x_bf)[i] = ((const uint4*)xv)[i];
    }
}

// ---------------------------------------------------------------------------
__global__ __launch_bounds__(256) void zero_kernel(float* __restrict__ z, long long n)
{
    long long i = (long long)blockIdx.x * 256 + threadIdx.x;
    long long stride = (long long)gridDim.x * 256;
    for (; i < n; i += stride) z[i] = 0.0f;
}

__device__ __forceinline__ int edge_at(const int* ei, long long pos, int is64) {
    return is64 ? ei[2 * pos] : ei[pos];
}

// ---------------------------------------------------------------------------
// CSR phase 1: in-degree counts (same validity predicate as fill).
// ---------------------------------------------------------------------------
__global__ __launch_bounds__(256) void count_kernel(
    const int* __restrict__ ei, int* __restrict__ cnt,
    const int* __restrict__ flags, int E, int N)
{
    int e = blockIdx.x * 256 + threadIdx.x;
    if (e >= E) return;
    int is64 = flags[0];
    int src = edge_at(ei, e, is64);
    int dst = edge_at(ei, (long long)E + e, is64);
    if ((unsigned)src >= (unsigned)N || (unsigned)dst >= (unsigned)N) return;
    atomicAdd(&cnt[dst], 1);
}

// ---------------------------------------------------------------------------
// CSR phase 2 (NEW, replaces single-block scan): order-free range allocation.
// Wave shuffle-scan of 64 counts -> one atomicAdd per wave on flags[4].
// row_start[n] gets a disjoint range; global ordering irrelevant for fill/agg.
// ---------------------------------------------------------------------------
__global__ __launch_bounds__(256) void offset_kernel(
    const int* __restrict__ cnt, int* __restrict__ row_start,
    int* __restrict__ counter, int N)
{
    int i = blockIdx.x * 256 + threadIdx.x;
    int lane = threadIdx.x & 63;
    int v0 = (i < N) ? cnt[i] : 0;
    int v = v0;
    #pragma unroll
    for (int off = 1; off < 64; off <<= 1) {
        int t = __shfl_up(v, off, 64);
        if (lane >= off) v += t;
    }
    int total = __shfl(v, 63, 64);
    int base = 0;
    if (lane == 0) base = atomicAdd(counter, total);
    base = __shfl(base, 0, 64);
    if (i < N) row_start[i] = base + v - v0;   // exclusive prefix within wave
}

// ---------------------------------------------------------------------------
// CSR phase 3: bucket-fill sources.
// ---------------------------------------------------------------------------
__global__ __launch_bounds__(256) void fill_kernel(
    const int* __restrict__ ei, const int* __restrict__ row_start,
    int* __restrict__ cursor, int* __restrict__ csr_src,
    const int* __restrict__ flags, int E, int N)
{
    int e = blockIdx.x * 256 + threadIdx.x;
    if (e >= E) return;
    int is64 = flags[0];
    int src = edge_at(ei, e, is64);
    int dst = edge_at(ei, (long long)E + e, is64);
    if ((unsigned)src >= (unsigned)N || (unsigned)dst >= (unsigned)N) return;
    int pos = atomicAdd(&cursor[dst], 1);
    csr_src[row_start[dst] + pos] = src;
}

// ---------------------------------------------------------------------------
// CSR phase 4: gather bf16 x rows, mean -> bf16. One wave per node:
// 4 edge-slots x 16 feature-groups (8 bf16 each). end = start + cnt[n].
// ---------------------------------------------------------------------------
__global__ __launch_bounds__(256) void aggregate_kernel(
    const unsigned short* __restrict__ x_bf, const int* __restrict__ csr_src,
    const int* __restrict__ row_start, const int* __restrict__ cnt,
    unsigned short* __restrict__ mean_bf, int N)
{
    int wave = threadIdx.x >> 6;
    int lane = threadIdx.x & 63;
    int n = blockIdx.x * 4 + wave;
    if (n >= N) return;
    int g = lane & 15, slot = lane >> 4;
    int start = row_start[n];
    int deg   = cnt[n];
    int end   = start + deg;
    float acc[8] = {0, 0, 0, 0, 0, 0, 0, 0};
    for (int i = start + slot; i < end; i += 4) {
        int src = csr_src[i];
        uint4 p = ((const uint4*)x_bf)[(long long)src * 16 + g];
        acc[0] += bf2f((unsigned short)(p.x & 0xFFFF));
        acc[1] += bf2f((unsigned short)(p.x >> 16));
        acc[2] += bf2f((unsigned short)(p.y & 0xFFFF));
        acc[3] += bf2f((unsigned short)(p.y >> 16));
        acc[4] += bf2f((unsigned short)(p.z & 0xFFFF));
        acc[5] += bf2f((unsigned short)(p.z >> 16));
        acc[6] += bf2f((unsigned short)(p.w & 0xFFFF));
        acc[7] += bf2f((unsigned short)(p.w >> 16));
    }
    #pragma unroll
    for (int j = 0; j < 8; ++j) {
        acc[j] += __shfl_xor(acc[j], 16, 64);
        acc[j] += __shfl_xor(acc[j], 32, 64);
    }
    if (slot == 0) {
        float inv = 1.0f / fmaxf((float)deg, 1.0f);
        uint4 p;
        p.x = (unsigned int)f2bf(acc[0] * inv) | ((unsigned int)f2bf(acc[1] * inv) << 16);
        p.y = (unsigned int)f2bf(acc[2] * inv) | ((unsigned int)f2bf(acc[3] * inv) << 16);
        p.z = (unsigned int)f2bf(acc[4] * inv) | ((unsigned int)f2bf(acc[5] * inv) << 16);
        p.w = (unsigned int)f2bf(acc[6] * inv) | ((unsigned int)f2bf(acc[7] * inv) << 16);
        ((uint4*)(mean_bf + (long long)n * FDIM + g * 8))[0] = p;
    }
}

// ---------------------------------------------------------------------------
// MFMA GEMM: h = relu([mean|x]_bf16 @ Wc^T + bl) -> out (f32/bf16 per flag)
// + BN column stats.
// ---------------------------------------------------------------------------
__global__ __launch_bounds__(256) void mfma_gemm_kernel(
    const unsigned short* __restrict__ mean_bf,
    const unsigned short* __restrict__ x_bf,
    const unsigned short* __restrict__ Wc_ws,   // [128][256] bf16
    const float* __restrict__ bl32,
    void* __restrict__ out,
    float* __restrict__ col_sum,                // [128] sums then [128] sqs
    const int* __restrict__ flags, int N)
{
    __shared__ unsigned short Wc[FDIM * LDS_STRIDE];
    int f32out = flags[1];

    for (int i = threadIdx.x; i < FDIM * 32; i += 256) {
        int row = i >> 5;
        int g8  = i & 31;
        *(uint4*)(Wc + row * LDS_STRIDE + g8 * 8) =
            *(const uint4*)(Wc_ws + row * 256 + g8 * 8);
    }
    __syncthreads();

    int wave = threadIdx.x >> 6;
    int lane = threadIdx.x & 63;
    int m    = lane & 15;
    int quad = lane >> 4;

    float bias[8];
    #pragma unroll
    for (int c = 0; c < 8; ++c) bias[c] = bl32[c * 16 + m];

    float lsum[8] = {0,0,0,0,0,0,0,0};
    float lsq[8]  = {0,0,0,0,0,0,0,0};

    int nst = (N + 31) >> 5;
    for (int st = blockIdx.x * 4 + wave; st < nst; st += gridDim.x * 4) {
        int r0 = st * 32;
        v4f acc[8][2];
        #pragma unroll
        for (int c = 0; c < 8; ++c) {
            acc[c][0] = (v4f){0.f, 0.f, 0.f, 0.f};
            acc[c][1] = (v4f){0.f, 0.f, 0.f, 0.f};
        }
        int ra = r0 + m;      if (ra > N - 1) ra = N - 1;
        int rb = r0 + 16 + m; if (rb > N - 1) rb = N - 1;
        #pragma unroll
        for (int kk = 0; kk < 8; ++kk) {
            const unsigned short* base = (kk < 4) ? mean_bf : x_bf;
            int koff = (kk & 3) * 32 + quad * 8;
            v8s a0 = *(const v8s*)(base + (long long)ra * FDIM + koff);
            v8s a1 = *(const v8s*)(base + (long long)rb * FDIM + koff);
            #pragma unroll
            for (int c = 0; c < 8; ++c) {
                v8s b = *(const v8s*)(Wc + (c * 16 + m) * LDS_STRIDE + kk * 32 + quad * 8);
                acc[c][0] = __builtin_amdgcn_mfma_f32_16x16x32_bf16(a0, b, acc[c][0], 0, 0, 0);
                acc[c][1] = __builtin_amdgcn_mfma_f32_16x16x32_bf16(a1, b, acc[c][1], 0, 0, 0);
            }
        }
        #pragma unroll
        for (int c = 0; c < 8; ++c) {
            #pragma unroll
            for (int t = 0; t < 2; ++t) {
                #pragma unroll
                for (int reg = 0; reg < 4; ++reg) {
                    int row = r0 + t * 16 + quad * 4 + reg;
                    if (row < N) {
                        float v = acc[c][t][reg] + bias[c];
                        v = fmaxf(v, 0.0f);
                        if (f32out) ((float*)out)[(long long)row * FDIM + c * 16 + m] = v;
                        else ((unsigned short*)out)[(long long)row * FDIM + c * 16 + m] = f2bf(v);
                        lsum[c] += v;
                        lsq[c]  += v * v;
                    }
                }
            }
        }
    }

    __syncthreads();
    float* red = (float*)Wc;
    red[threadIdx.x] = 0.0f;
    __syncthreads();
    #pragma unroll
    for (int c = 0; c < 8; ++c) {
        atomicAdd(&red[c * 16 + m],       lsum[c]);
        atomicAdd(&red[128 + c * 16 + m], lsq[c]);
    }
    __syncthreads();
    atomicAdd(&col_sum[threadIdx.x], red[threadIdx.x]);
}

// ---------------------------------------------------------------------------
// Fallback scatter + vector GEMM (only if ws too small for CSR).
// ---------------------------------------------------------------------------
__global__ __launch_bounds__(256) void scatter_kernel(
    const void* __restrict__ xv, const int* __restrict__ ei,
    float* __restrict__ agg, float* __restrict__ deg,
    const int* __restrict__ flags, int E, int N)
{
    long long idx = (long long)blockIdx.x * 256 + threadIdx.x;
    if (idx >= (long long)E * 16) return;
    int e = (int)(idx >> 4);
    int g = (int)(idx & 15);
    int is64 = flags[0];
    int src = edge_at(ei, e, is64);
    int dst = edge_at(ei, (long long)E + e, is64);
    if ((unsigned)src >= (unsigned)N || (unsigned)dst >= (unsigned)N) return;
    float v[8];
    if (flags[1]) {
        const float4* xr = (const float4*)xv;
        float4 a = xr[(long long)src * 32 + g * 2];
        float4 b = xr[(long long)src * 32 + g * 2 + 1];
        v[0] = a.x; v[1] = a.y; v[2] = a.z; v[3] = a.w;
        v[4] = b.x; v[5] = b.y; v[6] = b.z; v[7] = b.w;
    } else {
        uint4 p = ((const uint4*)xv)[(long long)src * 16 + g];
        v[0] = bf2f((unsigned short)(p.x & 0xFFFF)); v[1] = bf2f((unsigned short)(p.x >> 16));
        v[2] = bf2f((unsigned short)(p.y & 0xFFFF)); v[3] = bf2f((unsigned short)(p.y >> 16));
        v[4] = bf2f((unsigned short)(p.z & 0xFFFF)); v[5] = bf2f((unsigned short)(p.z >> 16));
        v[6] = bf2f((unsigned short)(p.w & 0xFFFF)); v[7] = bf2f((unsigned short)(p.w >> 16));
    }
    float* a = agg + (long long)dst * FDIM + g * 8;
    #pragma unroll
    for (int j = 0; j < 8; ++j) atomicAdd(a + j, v[j]);
    if (g == 0) atomicAdd(deg + dst, 1.0f);
}

__global__ __launch_bounds__(512) void gemm_kernel(
    const float* __restrict__ agg, const float* __restrict__ deg,
    const void* __restrict__ xv,
    const float* __restrict__ Wl32, const float* __restrict__ bl32,
    const float* __restrict__ Wr32,
    void* __restrict__ out,
    float* __restrict__ col_sum, float* __restrict__ col_sq,
    const int* __restrict__ flags, int nodes)
{
    __shared__ float mrow[4][FDIM];
    __shared__ float xrow[4][FDIM];
    int tid  = threadIdx.x;
    int slot = tid >> 7;
    int d    = tid & 127;
    int f32  = flags[1];
    float lsum = 0.0f, lsq = 0.0f;
    int ngroups = (nodes + 3) >> 2;
    for (int g = blockIdx.x; g < ngroups; g += gridDim.x) {
        int n = g * 4 + slot;
        __syncthreads();
        if (n < nodes) {
            float inv = 1.0f / fmaxf(deg[n], 1.0f);
            mrow[slot][d] = agg[(long long)n * FDIM + d] * inv;
            xrow[slot][d] = f32 ? ((const float*)xv)[(long long)n * FDIM + d]
                                : bf2f(((const unsigned short*)xv)[(long long)n * FDIM + d]);
        }
        __syncthreads();
        if (n < nodes) {
            float acc = bl32[d];
            const float4* wl4 = (const float4*)(Wl32 + d * FDIM);
            const float4* wr4 = (const float4*)(Wr32 + d * FDIM);
            const float* mr = mrow[slot];
            const float* xr = xrow[slot];
            #pragma unroll
            for (int c = 0; c < 32; ++c) {
                float4 wa = wl4[c];
                float4 wb = wr4[c];
                int k = c * 4;
                acc += wa.x * mr[k] + wa.y * mr[k + 1] + wa.z * mr[k + 2] + wa.w * mr[k + 3];
                acc += wb.x * xr[k] + wb.y * xr[k + 1] + wb.z * xr[k + 2] + wb.w * xr[k + 3];
            }
            acc = fmaxf(acc, 0.0f);
            if (f32) ((float*)out)[(long long)n * FDIM + d] = acc;
            else     ((unsigned short*)out)[(long long)n * FDIM + d] = f2bf(acc);
            lsum += acc;
            lsq  += acc * acc;
        }
    }
    __syncthreads();
    mrow[slot][d] = lsum;
    xrow[slot][d] = lsq;
    __syncthreads();
    if (slot == 0) {
        atomicAdd(&col_sum[d], mrow[0][d] + mrow[1][d] + mrow[2][d] + mrow[3][d]);
        atomicAdd(&col_sq[d],  xrow[0][d] + xrow[1][d] + xrow[2][d] + xrow[3][d]);
    }
}

// ---------------------------------------------------------------------------
__global__ void bn_prep(const float* __restrict__ col_sum, const float* __restrict__ col_sq,
                        const float* __restrict__ gm32, const float* __restrict__ bt32,
                        float* __restrict__ scale, float* __restrict__ shift, int nodes)
{
    int d = threadIdx.x;
    float invN = 1.0f / (float)nodes;
    float mu  = col_sum[d] * invN;
    float var = col_sq[d] * invN - mu * mu;
    float sc  = gm32[d] * rsqrtf(var + BN_EPS);
    scale[d] = sc;
    shift[d] = bt32[d] - mu * sc;
}

// ---------------------------------------------------------------------------
__global__ __launch_bounds__(256) void ChemSageBlock_89206470738295_kernel(
    void* __restrict__ hv,
    const float* __restrict__ scale, const float* __restrict__ shift,
    const int* __restrict__ flags, long long nd)
{
    long long idx = (long long)blockIdx.x * 256 + threadIdx.x;
    if (flags[1]) {
        long long tot = nd >> 2;
        if (idx >= tot) return;
        int d0 = (int)(idx & 31) * 4;
        float4 p = ((float4*)hv)[idx];
        p.x = p.x * scale[d0 + 0] + shift[d0 + 0];
        p.y = p.y * scale[d0 + 1] + shift[d0 + 1];
        p.z = p.z * scale[d0 + 2] + shift[d0 + 2];
        p.w = p.w * scale[d0 + 3] + shift[d0 + 3];
        ((float4*)hv)[idx] = p;
    } else {
        long long tot = nd >> 3;
        if (idx >= tot) return;
        int d0 = (int)(idx & 15) * 8;
        uint4 p = ((uint4*)hv)[idx];
        unsigned int q[4] = {p.x, p.y, p.z, p.w};
        #pragma unroll
        for (int j = 0; j < 4; ++j) {
            int dd = d0 + j * 2;
            float lo = bf2f((unsigned short)(q[j] & 0xFFFF));
            float hi = bf2f((unsigned short)(q[j] >> 16));
            lo = lo * scale[dd]     + shift[dd];
            hi = hi * scale[dd + 1] + shift[dd + 1];
            q[j] = (unsigned int)f2bf(lo) | ((unsigned int)f2bf(hi) << 16);
        }
        uint4 r; r.x = q[0]; r.y = q[1]; r.z = q[2]; r.w = q[3];
        ((uint4*)hv)[idx] = r;
    }
}

// ---------------------------------------------------------------------------
extern "C" __attribute__((visibility("default")))
void kernel_launch(void* const* d_in, const int* in_sizes, int n_in,
                   void* d_out, int out_size, void* d_ws, size_t ws_size,
                   hipStream_t stream)
{
    int N = 100000, E = 1600000;
    if (in_sizes) {
        if (in_sizes[0] > 0 && (in_sizes[0] % FDIM) == 0) N = in_sizes[0] / FDIM;
        if (in_sizes[1] > 0 && (in_sizes[1] % 2) == 0)    E = in_sizes[1] / 2;
    }
    const void* x  = d_in[0];
    const int*  ei = (const int*)d_in[1];
    const void* Wl = d_in[2];
    const void* bl = d_in[3];
    const void* Wr = d_in[4];
    const void* gm = d_in[5];
    const void* bt = d_in[6];

    unsigned short* x_bf    = (unsigned short*)d_ws;
    unsigned short* mean_bf = x_bf + (size_t)N * FDIM;
    unsigned short* Wc      = mean_bf + (size_t)N * FDIM;
    float* Wl32    = (float*)(Wc + FDIM * 256);
    float* Wr32    = Wl32 + FDIM * FDIM;
    float* bl32    = Wr32 + FDIM * FDIM;
    float* gm32    = bl32 + FDIM;
    float* bt32    = gm32 + FDIM;
    float* scale   = bt32 + FDIM;
    float* shift   = scale + FDIM;
    float* col_sum = shift + FDIM;
    float* col_sq  = col_sum + FDIM;
    int*   cnt     = (int*)(col_sq + FDIM);
    int*   cursor  = cnt + N;
    int*   row_st  = cursor + N;
    int*   csr_src = row_st + N + 64;
    int*   flags   = csr_src + E;
    size_t ws_need = (size_t)((char*)(flags + 16) - (char*)d_ws);

    detect_convert_kernel<<<1, 1024, 0, stream>>>(
        (const unsigned int*)x, ei, Wl, bl, Wr, gm, bt,
        Wc, Wl32, Wr32, bl32, gm32, bt32, flags);

    int eblocks = (E + 255) / 256;
    int nblocks = (N + 255) / 256;
    long long nd = (long long)N * FDIM;

    if (ws_size >= ws_need) {
        // CSR + MFMA path
        long long n8 = nd >> 3;
        convert_x_kernel<<<(int)((n8 + 255) / 256), 256, 0, stream>>>(x, x_bf, flags, n8);
        zero_kernel<<<512, 256, 0, stream>>>(col_sum, 2 * FDIM + 2 * (long long)N);
        count_kernel<<<eblocks, 256, 0, stream>>>(ei, cnt, flags, E, N);
        offset_kernel<<<nblocks, 256, 0, stream>>>(cnt, row_st, &flags[4], N);
        fill_kernel<<<eblocks, 256, 0, stream>>>(ei, row_st, cursor, csr_src, flags, E, N);
        aggregate_kernel<<<(N + 3) / 4, 256, 0, stream>>>(
            x_bf, csr_src, row_st, cnt, mean_bf, N);
        mfma_gemm_kernel<<<512, 256, 0, stream>>>(
            mean_bf, x_bf, Wc, bl32, d_out, col_sum, flags, N);
    } else {
        // Fallback: atomic scatter + vector GEMM. agg f32 aliases x_bf+mean_bf.
        float* agg = (float*)d_ws;
        zero_kernel<<<2048, 256, 0, stream>>>(agg, nd);
        zero_kernel<<<512, 256, 0, stream>>>(col_sum, 2 * FDIM + (long long)N);
        long long sc_threads = (long long)E * 16;
        scatter_kernel<<<(int)((sc_threads + 255) / 256), 256, 0, stream>>>(
            x, ei, agg, (float*)cnt, flags, E, N);
        gemm_kernel<<<2048, 512, 0, stream>>>(agg, (const float*)cnt, x, Wl32, bl32, Wr32,
                                              d_out, col_sum, col_sq, flags, N);
    }

    bn_prep<<<1, 128, 0, stream>>>(col_sum, col_sq, gm32, bt32, scale, shift, N);

    ChemSageBlock_89206470738295_kernel<<<(int)((nd / 4 + 255) / 256), 256, 0, stream>>>(
        d_out, scale, shift, flags, nd);
}